// Round 1
// baseline (572.020 us; speedup 1.0000x reference)
//
#include <hip/hip_runtime.h>
#include <math.h>

#define INF_ 100000.0f
constexpr int B_ = 64, W_ = 16, T_ = 64, U_ = 128, S_ = 20, N_ = 8;

// ---------------------------------------------------------------------------
// K1: per (b,w): p = softmax(c @ h^T) over T (with p==0 -> -INF mask),
//     q_slot = p @ h + pos.   grid = B*W = 1024 blocks, 256 threads.
// h staged transposed [u][t] with +1 pad: conflict-free for both phases.
// ---------------------------------------------------------------------------
__global__ __launch_bounds__(256) void k1_attn(
    const float* __restrict__ h,    // [B,W,T,U]
    const float* __restrict__ c,    // [S,U]
    const float* __restrict__ pos,  // [B,W,S,U]
    float* __restrict__ q_slot)     // [B,W,S,U]
{
    __shared__ __align__(16) float sh_hT[U_][T_ + 1];  // 33280 B
    __shared__ __align__(16) float sh_c[S_ * U_];      // 10240 B
    __shared__ __align__(16) float sh_p[S_][T_];       // 5120 B

    const int bw = blockIdx.x;
    const int tid = threadIdx.x;
    const float* hb = h + (size_t)bw * T_ * U_;

    // load h transposed (global read coalesced, LDS write stride 65 -> conflict-free)
    for (int i = tid; i < T_ * U_; i += 256) {
        int t = i >> 7, u = i & 127;
        sh_hT[u][t] = hb[i];
    }
    for (int i = tid; i < S_ * U_; i += 256) sh_c[i] = c[i];
    __syncthreads();

    // scores p[s,t] = sum_u c[s,u] h[t,u]
    for (int i = tid; i < S_ * T_; i += 256) {
        int s = i >> 6, t = i & 63;      // per 64-lane group: s uniform, t = lane
        const float* cs = sh_c + s * U_;
        float acc = 0.f;
#pragma unroll 8
        for (int u = 0; u < U_; ++u) acc += cs[u] * sh_hT[u][t];
        sh_p[s][t] = acc;
    }
    __syncthreads();

    // softmax over t (one wave per row, T == 64 == wave size)
    const int wave = tid >> 6, lane = tid & 63;
    for (int s = wave; s < S_; s += 4) {
        float v = sh_p[s][lane];
        if (v == 0.0f) v = -INF_;        // zero-mask semantics
        float m = v;
        for (int d = 32; d >= 1; d >>= 1) m = fmaxf(m, __shfl_xor(m, d));
        float e = expf(v - m);
        float sum = e;
        for (int d = 32; d >= 1; d >>= 1) sum += __shfl_xor(sum, d);
        sh_p[s][lane] = e / sum;
    }
    __syncthreads();

    // q_slot[s,u] = sum_t p[s,t] h[t,u] + pos
    const float* pb = pos + (size_t)bw * S_ * U_;
    float* qb = q_slot + (size_t)bw * S_ * U_;
    for (int i = tid; i < S_ * U_; i += 256) {
        int s = i >> 7, u = i & 127;     // per 64-lane group: s uniform, u consecutive
        float acc = 0.f;
#pragma unroll 8
        for (int t = 0; t < T_; ++t) acc += sh_p[s][t] * sh_hT[u][t];
        qb[i] = acc + pb[i];
    }
}

// ---------------------------------------------------------------------------
// K2a: [qw | A] = q_slot @ [weight | W1_top],  A += b1.
// M = B*W*S = 20480, K = 128, Nout = 256. grid = M/32 = 640 blocks.
// ---------------------------------------------------------------------------
__global__ __launch_bounds__(256) void k2_qw_a(
    const float* __restrict__ q_slot,  // [M][128]
    const float* __restrict__ weight,  // [128][128]
    const float* __restrict__ W1,      // [256][128]
    const float* __restrict__ b1,      // [128]
    float* __restrict__ qw,            // [M][128]
    float* __restrict__ A)             // [M][128]
{
    __shared__ __align__(16) float sh_w[U_][256];  // 128 KB
    __shared__ __align__(16) float sh_x[32 * U_];  // 16 KB
    __shared__ __align__(16) float sh_b1[U_];

    const int tid = threadIdx.x;
    const int row0 = blockIdx.x * 32;

    for (int i = tid * 4; i < U_ * 256; i += 1024) {
        int k = i >> 8, j = i & 255;
        const float* src = (j < 128) ? (weight + k * 128 + j) : (W1 + k * 128 + (j - 128));
        *(float4*)&sh_w[k][j] = *(const float4*)src;
    }
    for (int i = tid * 4; i < 32 * U_; i += 1024)
        *(float4*)&sh_x[i] = *(const float4*)(q_slot + (size_t)row0 * U_ + i);
    if (tid < 128) sh_b1[tid] = b1[tid];
    __syncthreads();

    const int rg = tid >> 5;   // 8 groups of 4 rows
    const int jg = tid & 31;   // 32 groups of 8 cols
    float acc[4][8];
#pragma unroll
    for (int i = 0; i < 4; ++i)
#pragma unroll
        for (int j = 0; j < 8; ++j) acc[i][j] = 0.f;

    for (int k = 0; k < U_; ++k) {
        float xv[4];
#pragma unroll
        for (int i = 0; i < 4; ++i) xv[i] = sh_x[(rg * 4 + i) * U_ + k];
        float4 wa = *(float4*)&sh_w[k][jg * 8];
        float4 wb = *(float4*)&sh_w[k][jg * 8 + 4];
#pragma unroll
        for (int i = 0; i < 4; ++i) {
            acc[i][0] += xv[i] * wa.x; acc[i][1] += xv[i] * wa.y;
            acc[i][2] += xv[i] * wa.z; acc[i][3] += xv[i] * wa.w;
            acc[i][4] += xv[i] * wb.x; acc[i][5] += xv[i] * wb.y;
            acc[i][6] += xv[i] * wb.z; acc[i][7] += xv[i] * wb.w;
        }
    }

#pragma unroll
    for (int i = 0; i < 4; ++i) {
        int row = row0 + rg * 4 + i;
        if (jg < 16) {
            float4 o0 = {acc[i][0], acc[i][1], acc[i][2], acc[i][3]};
            float4 o1 = {acc[i][4], acc[i][5], acc[i][6], acc[i][7]};
            *(float4*)(qw + (size_t)row * U_ + jg * 8) = o0;
            *(float4*)(qw + (size_t)row * U_ + jg * 8 + 4) = o1;
        } else {
            int j = (jg - 16) * 8;
            float4 o0 = {acc[i][0] + sh_b1[j],     acc[i][1] + sh_b1[j + 1],
                         acc[i][2] + sh_b1[j + 2], acc[i][3] + sh_b1[j + 3]};
            float4 o1 = {acc[i][4] + sh_b1[j + 4], acc[i][5] + sh_b1[j + 5],
                         acc[i][6] + sh_b1[j + 6], acc[i][7] + sh_b1[j + 7]};
            *(float4*)(A + (size_t)row * U_ + j) = o0;
            *(float4*)(A + (size_t)row * U_ + j + 4) = o1;
        }
    }
}

// ---------------------------------------------------------------------------
// K2b: QS1 = q_status @ W1_bot.  M = B*W*N = 8192 rows. grid = 256 blocks.
// ---------------------------------------------------------------------------
__global__ __launch_bounds__(256) void k2_qs1(
    const float* __restrict__ q_status,  // [8192][128]
    const float* __restrict__ W1,        // rows 128..255 used
    float* __restrict__ QS1)             // [8192][128]
{
    __shared__ __align__(16) float sh_w[U_][U_];   // 64 KB
    __shared__ __align__(16) float sh_x[32 * U_];  // 16 KB

    const int tid = threadIdx.x;
    const int row0 = blockIdx.x * 32;

    for (int i = tid * 4; i < U_ * U_; i += 1024)
        *(float4*)&sh_w[0][i] = *(const float4*)(W1 + 128 * 128 + i);  // W1_bot
    for (int i = tid * 4; i < 32 * U_; i += 1024)
        *(float4*)&sh_x[i] = *(const float4*)(q_status + (size_t)row0 * U_ + i);
    __syncthreads();

    const int rg = tid >> 5;
    const int jg = tid & 31;
    float acc[4][4];
#pragma unroll
    for (int i = 0; i < 4; ++i)
#pragma unroll
        for (int j = 0; j < 4; ++j) acc[i][j] = 0.f;

    for (int k = 0; k < U_; ++k) {
        float4 w4 = *(float4*)&sh_w[k][jg * 4];
#pragma unroll
        for (int i = 0; i < 4; ++i) {
            float xv = sh_x[(rg * 4 + i) * U_ + k];
            acc[i][0] += xv * w4.x; acc[i][1] += xv * w4.y;
            acc[i][2] += xv * w4.z; acc[i][3] += xv * w4.w;
        }
    }
#pragma unroll
    for (int i = 0; i < 4; ++i) {
        int row = row0 + rg * 4 + i;
        float4 o = {acc[i][0], acc[i][1], acc[i][2], acc[i][3]};
        *(float4*)(QS1 + (size_t)row * U_ + jg * 4) = o;
    }
}

// ---------------------------------------------------------------------------
// K3: co[b] = qw[b] @ q_status[b]^T   ([320,128] x [128,128]^T per batch).
// grid = (10, 64).  q_status staged transposed (+4 pad) for b128 reads.
// ---------------------------------------------------------------------------
__global__ __launch_bounds__(256) void k3_co(
    const float* __restrict__ qw,        // [B][320][128]
    const float* __restrict__ q_status,  // [B][128][128]
    float* __restrict__ co)              // [B][320][128]
{
    __shared__ __align__(16) float sh_yT[U_][132];  // 67584 B
    __shared__ __align__(16) float sh_x[32 * U_];   // 16 KB

    const int tid = threadIdx.x;
    const int b = blockIdx.y;
    const int rt = blockIdx.x;  // 0..9

    const float* xs = qw + ((size_t)b * 320 + rt * 32) * U_;
    for (int i = tid * 4; i < 32 * U_; i += 1024)
        *(float4*)&sh_x[i] = *(const float4*)(xs + i);
    const float* ys = q_status + (size_t)b * 128 * U_;
    for (int i = tid; i < 128 * U_; i += 256) {
        int xn = i >> 7, v = i & 127;
        sh_yT[v][xn] = ys[i];
    }
    __syncthreads();

    const int rg = tid >> 5;
    const int cg = tid & 31;
    float acc[4][4];
#pragma unroll
    for (int i = 0; i < 4; ++i)
#pragma unroll
        for (int j = 0; j < 4; ++j) acc[i][j] = 0.f;

    for (int k = 0; k < U_; ++k) {
        float4 y4 = *(float4*)&sh_yT[k][cg * 4];
#pragma unroll
        for (int i = 0; i < 4; ++i) {
            float xv = sh_x[(rg * 4 + i) * U_ + k];
            acc[i][0] += xv * y4.x; acc[i][1] += xv * y4.y;
            acc[i][2] += xv * y4.z; acc[i][3] += xv * y4.w;
        }
    }
#pragma unroll
    for (int i = 0; i < 4; ++i) {
        int row = rt * 32 + rg * 4 + i;
        float4 o = {acc[i][0], acc[i][1], acc[i][2], acc[i][3]};
        *(float4*)(co + ((size_t)b * 320 + row) * U_ + cg * 4) = o;
    }
}

// ---------------------------------------------------------------------------
// K4 (dominant): per (b,w): loop s: softmax over x -> h1 -> h2 -> logit.
// LDS: QS1[b] (64 KB) + W2 (64 KB) + h1 (4 KB) + small.  grid = 1024 blocks.
// ---------------------------------------------------------------------------
__global__ __launch_bounds__(256) void k4_fused(
    const float* __restrict__ co,   // [B][320][128]
    const float* __restrict__ QS1,  // [B][128][128]
    const float* __restrict__ A,    // [B*W*S][128]  (includes b1)
    const float* __restrict__ W2,   // [128][128]
    const float* __restrict__ b2,   // [128]
    const float* __restrict__ W3,   // [128]
    const float* __restrict__ b3,   // [1]
    float* __restrict__ lg)         // [B][W][160]
{
    __shared__ __align__(16) float sh_qs1[U_ * U_];  // 64 KB  [xn][u]
    __shared__ __align__(16) float sh_w2[U_ * U_];   // 64 KB  [u][j]
    __shared__ __align__(16) float sh_h1[N_ * U_];   // 4 KB
    __shared__ __align__(16) float sh_a[U_];
    __shared__ __align__(16) float sh_co[U_];
    __shared__ __align__(16) float sh_p2[U_];        // [x][n] = 16*8
    __shared__ __align__(16) float sh_w3[U_];
    __shared__ __align__(16) float sh_b2[U_];
    __shared__ float sh_b3;

    const int bw = blockIdx.x;
    const int b = bw >> 4;
    const int tid = threadIdx.x;

    const float* qs1b = QS1 + (size_t)b * U_ * U_;
    for (int i = tid * 4; i < U_ * U_; i += 1024) {
        *(float4*)&sh_qs1[i] = *(const float4*)&qs1b[i];
        *(float4*)&sh_w2[i] = *(const float4*)&W2[i];
    }
    if (tid < 128) { sh_w3[tid] = W3[tid]; sh_b2[tid] = b2[tid]; }
    if (tid == 0) sh_b3 = b3[0];

    const int n8 = tid >> 5;   // n for h2 phase
    const int jg = tid & 31;   // 4-col group for h2 phase

    for (int s = 0; s < S_; ++s) {
        const int rowbase = (bw * S_ + s) * U_;
        if (tid < 128) {
            sh_a[tid] = A[rowbase + tid];
            sh_co[tid] = co[rowbase + tid];
        }
        __syncthreads();

        // softmax over x for each n (wave 0; 2 x-values per lane)
        if (tid < 64) {
            int n = tid & 7, x0 = tid >> 3;
            float v0 = sh_co[x0 * 8 + n];
            float v1 = sh_co[(x0 + 8) * 8 + n];
            if (v0 == 0.0f) v0 = -INF_;
            if (v1 == 0.0f) v1 = -INF_;
            float m = fmaxf(v0, v1);
            m = fmaxf(m, __shfl_xor(m, 8));
            m = fmaxf(m, __shfl_xor(m, 16));
            m = fmaxf(m, __shfl_xor(m, 32));
            float e0 = expf(v0 - m), e1 = expf(v1 - m);
            float sm = e0 + e1;
            sm += __shfl_xor(sm, 8);
            sm += __shfl_xor(sm, 16);
            sm += __shfl_xor(sm, 32);
            float r = 1.0f / sm;
            sh_p2[x0 * 8 + n] = e0 * r;
            sh_p2[(x0 + 8) * 8 + n] = e1 * r;
        }
        __syncthreads();

        // h1[n][u] = relu(A[u] + sum_x p2[x,n]*QS1[x,n,u])
#pragma unroll
        for (int k = 0; k < 4; ++k) {
            int idx = tid + k * 256;
            int n = idx >> 7, u = idx & 127;
            float acc = sh_a[u];
#pragma unroll
            for (int x = 0; x < 16; ++x)
                acc += sh_p2[x * 8 + n] * sh_qs1[(x * 8 + n) * U_ + u];
            sh_h1[idx] = fmaxf(acc, 0.f);
        }
        __syncthreads();

        // h2[n][j] = relu(h1[n]@W2 + b2); logit[n] = h2[n]@W3 + b3
        float a0 = 0.f, a1 = 0.f, a2 = 0.f, a3 = 0.f;
        const float* h1n = sh_h1 + n8 * U_;
#pragma unroll 4
        for (int u = 0; u < U_; ++u) {
            float hv = h1n[u];
            float4 w4 = *(float4*)&sh_w2[u * U_ + jg * 4];
            a0 += hv * w4.x; a1 += hv * w4.y; a2 += hv * w4.z; a3 += hv * w4.w;
        }
        int j0 = jg * 4;
        float part = fmaxf(a0 + sh_b2[j0], 0.f) * sh_w3[j0]
                   + fmaxf(a1 + sh_b2[j0 + 1], 0.f) * sh_w3[j0 + 1]
                   + fmaxf(a2 + sh_b2[j0 + 2], 0.f) * sh_w3[j0 + 2]
                   + fmaxf(a3 + sh_b2[j0 + 3], 0.f) * sh_w3[j0 + 3];
        part += __shfl_xor(part, 1);
        part += __shfl_xor(part, 2);
        part += __shfl_xor(part, 4);
        part += __shfl_xor(part, 8);
        part += __shfl_xor(part, 16);
        if (jg == 0) lg[bw * (S_ * N_) + s * N_ + n8] = part + sh_b3;
        __syncthreads();
    }
}

// ---------------------------------------------------------------------------
// K5: masked max over W, labels, scalar.
// ---------------------------------------------------------------------------
__global__ __launch_bounds__(256) void k5_final(
    const float* __restrict__ lg,    // [B][W][160]
    const float* __restrict__ mask,  // [B][W][160]
    float* __restrict__ out)
{
    int idx = blockIdx.x * 256 + threadIdx.x;
    const int SN = S_ * N_;
    if (idx < B_ * SN) {
        int b = idx / SN, sn = idx % SN;
        float m = -INFINITY;
        for (int w = 0; w < W_; ++w) {
            float v = lg[((size_t)b * W_ + w) * SN + sn] + mask[((size_t)b * W_ + w) * SN + sn];
            m = fmaxf(m, v);
        }
        out[idx] = (m > 0.f) ? 1.f : 0.f;   // labels
        out[B_ * SN + 1 + idx] = m;         // logits
    }
    if (idx == 0) out[B_ * SN] = (float)SN; // scalar S*N = 160
}

// ---------------------------------------------------------------------------
extern "C" void kernel_launch(void* const* d_in, const int* in_sizes, int n_in,
                              void* d_out, int out_size, void* d_ws, size_t ws_size,
                              hipStream_t stream) {
    const float* slot_utt_h = (const float*)d_in[0];
    const float* slot_candidate_c = (const float*)d_in[1];
    // d_in[2] status_candidate_c: unused by the reference
    const float* position_encoding = (const float*)d_in[3];
    const float* q_status = (const float*)d_in[4];
    const float* mask = (const float*)d_in[5];
    const float* weight = (const float*)d_in[6];
    const float* W1 = (const float*)d_in[7];
    const float* b1 = (const float*)d_in[8];
    const float* W2 = (const float*)d_in[9];
    const float* b2 = (const float*)d_in[10];
    const float* W3 = (const float*)d_in[11];
    const float* b3 = (const float*)d_in[12];
    float* out = (float*)d_out;

    float* ws = (float*)d_ws;
    float* q_slot = ws;                  // B*W*S*U   = 2,621,440
    float* qw     = q_slot + 2621440;    //           = 2,621,440
    float* A      = qw + 2621440;        //           = 2,621,440
    float* QS1    = A + 2621440;         // B*W*N*U   = 1,048,576
    float* co     = QS1 + 1048576;       // B*320*128 = 2,621,440
    float* lg     = co + 2621440;        // B*W*160   =   163,840

    k1_attn<<<B_ * W_, 256, 0, stream>>>(slot_utt_h, slot_candidate_c,
                                         position_encoding, q_slot);
    k2_qw_a<<<(B_ * W_ * S_) / 32, 256, 0, stream>>>(q_slot, weight, W1, b1, qw, A);
    k2_qs1<<<(B_ * W_ * N_) / 32, 256, 0, stream>>>(q_status, W1, QS1);
    k3_co<<<dim3(10, B_), 256, 0, stream>>>(qw, q_status, co);
    k4_fused<<<B_ * W_, 256, 0, stream>>>(co, QS1, A, W2, b2, W3, b3, lg);
    k5_final<<<(B_ * S_ * N_ + 255) / 256, 256, 0, stream>>>(lg, mask, out);
}

// Round 2
// 326.765 us; speedup vs baseline: 1.7506x; 1.7506x over previous
//
#include <hip/hip_runtime.h>
#include <math.h>

#define INF_ 100000.0f
constexpr int B_ = 64, W_ = 16, T_ = 64, U_ = 128, S_ = 20, N_ = 8;

typedef __attribute__((ext_vector_type(8))) short bf16x8;
typedef __attribute__((ext_vector_type(4))) float floatx4;

static __device__ __forceinline__ unsigned short f2bf(float x) {
    unsigned int u = __float_as_uint(x);
    u = (u + 0x7fff + ((u >> 16) & 1)) >> 16;   // RNE
    return (unsigned short)u;
}

// ---------------------------------------------------------------------------
// K1: per (b,w): p = softmax(c @ h^T) over T (with p==0 -> -INF mask),
//     q_slot = p @ h + pos.   grid = B*W = 1024 blocks, 256 threads.
// ---------------------------------------------------------------------------
__global__ __launch_bounds__(256) void k1_attn(
    const float* __restrict__ h,    // [B,W,T,U]
    const float* __restrict__ c,    // [S,U]
    const float* __restrict__ pos,  // [B,W,S,U]
    float* __restrict__ q_slot)     // [B,W,S,U]
{
    __shared__ __align__(16) float sh_hT[U_][T_ + 1];
    __shared__ __align__(16) float sh_c[S_ * U_];
    __shared__ __align__(16) float sh_p[S_][T_];

    const int bw = blockIdx.x;
    const int tid = threadIdx.x;
    const float* hb = h + (size_t)bw * T_ * U_;

    for (int i = tid; i < T_ * U_; i += 256) {
        int t = i >> 7, u = i & 127;
        sh_hT[u][t] = hb[i];
    }
    for (int i = tid; i < S_ * U_; i += 256) sh_c[i] = c[i];
    __syncthreads();

    for (int i = tid; i < S_ * T_; i += 256) {
        int s = i >> 6, t = i & 63;
        const float* cs = sh_c + s * U_;
        float acc = 0.f;
#pragma unroll 8
        for (int u = 0; u < U_; ++u) acc += cs[u] * sh_hT[u][t];
        sh_p[s][t] = acc;
    }
    __syncthreads();

    const int wave = tid >> 6, lane = tid & 63;
    for (int s = wave; s < S_; s += 4) {
        float v = sh_p[s][lane];
        if (v == 0.0f) v = -INF_;
        float m = v;
        for (int d = 32; d >= 1; d >>= 1) m = fmaxf(m, __shfl_xor(m, d));
        float e = expf(v - m);
        float sum = e;
        for (int d = 32; d >= 1; d >>= 1) sum += __shfl_xor(sum, d);
        sh_p[s][lane] = e / sum;
    }
    __syncthreads();

    const float* pb = pos + (size_t)bw * S_ * U_;
    float* qb = q_slot + (size_t)bw * S_ * U_;
    for (int i = tid; i < S_ * U_; i += 256) {
        int s = i >> 7, u = i & 127;
        float acc = 0.f;
#pragma unroll 8
        for (int t = 0; t < T_; ++t) acc += sh_p[s][t] * sh_hT[u][t];
        qb[i] = acc + pb[i];
    }
}

// ---------------------------------------------------------------------------
// K2a: [qw | A] = q_slot @ [weight | W1_top],  A += b1.
// ---------------------------------------------------------------------------
__global__ __launch_bounds__(256) void k2_qw_a(
    const float* __restrict__ q_slot,
    const float* __restrict__ weight,
    const float* __restrict__ W1,
    const float* __restrict__ b1,
    float* __restrict__ qw,
    float* __restrict__ A)
{
    __shared__ __align__(16) float sh_w[U_][256];
    __shared__ __align__(16) float sh_x[32 * U_];
    __shared__ __align__(16) float sh_b1[U_];

    const int tid = threadIdx.x;
    const int row0 = blockIdx.x * 32;

    for (int i = tid * 4; i < U_ * 256; i += 1024) {
        int k = i >> 8, j = i & 255;
        const float* src = (j < 128) ? (weight + k * 128 + j) : (W1 + k * 128 + (j - 128));
        *(float4*)&sh_w[k][j] = *(const float4*)src;
    }
    for (int i = tid * 4; i < 32 * U_; i += 1024)
        *(float4*)&sh_x[i] = *(const float4*)(q_slot + (size_t)row0 * U_ + i);
    if (tid < 128) sh_b1[tid] = b1[tid];
    __syncthreads();

    const int rg = tid >> 5;
    const int jg = tid & 31;
    float acc[4][8];
#pragma unroll
    for (int i = 0; i < 4; ++i)
#pragma unroll
        for (int j = 0; j < 8; ++j) acc[i][j] = 0.f;

    for (int k = 0; k < U_; ++k) {
        float xv[4];
#pragma unroll
        for (int i = 0; i < 4; ++i) xv[i] = sh_x[(rg * 4 + i) * U_ + k];
        float4 wa = *(float4*)&sh_w[k][jg * 8];
        float4 wb = *(float4*)&sh_w[k][jg * 8 + 4];
#pragma unroll
        for (int i = 0; i < 4; ++i) {
            acc[i][0] += xv[i] * wa.x; acc[i][1] += xv[i] * wa.y;
            acc[i][2] += xv[i] * wa.z; acc[i][3] += xv[i] * wa.w;
            acc[i][4] += xv[i] * wb.x; acc[i][5] += xv[i] * wb.y;
            acc[i][6] += xv[i] * wb.z; acc[i][7] += xv[i] * wb.w;
        }
    }

#pragma unroll
    for (int i = 0; i < 4; ++i) {
        int row = row0 + rg * 4 + i;
        if (jg < 16) {
            float4 o0 = {acc[i][0], acc[i][1], acc[i][2], acc[i][3]};
            float4 o1 = {acc[i][4], acc[i][5], acc[i][6], acc[i][7]};
            *(float4*)(qw + (size_t)row * U_ + jg * 8) = o0;
            *(float4*)(qw + (size_t)row * U_ + jg * 8 + 4) = o1;
        } else {
            int j = (jg - 16) * 8;
            float4 o0 = {acc[i][0] + sh_b1[j],     acc[i][1] + sh_b1[j + 1],
                         acc[i][2] + sh_b1[j + 2], acc[i][3] + sh_b1[j + 3]};
            float4 o1 = {acc[i][4] + sh_b1[j + 4], acc[i][5] + sh_b1[j + 5],
                         acc[i][6] + sh_b1[j + 6], acc[i][7] + sh_b1[j + 7]};
            *(float4*)(A + (size_t)row * U_ + j) = o0;
            *(float4*)(A + (size_t)row * U_ + j + 4) = o1;
        }
    }
}

// ---------------------------------------------------------------------------
// K2b: QS1 = q_status @ W1_bot.
// ---------------------------------------------------------------------------
__global__ __launch_bounds__(256) void k2_qs1(
    const float* __restrict__ q_status,
    const float* __restrict__ W1,
    float* __restrict__ QS1)
{
    __shared__ __align__(16) float sh_w[U_][U_];
    __shared__ __align__(16) float sh_x[32 * U_];

    const int tid = threadIdx.x;
    const int row0 = blockIdx.x * 32;

    for (int i = tid * 4; i < U_ * U_; i += 1024)
        *(float4*)&sh_w[0][i] = *(const float4*)(W1 + 128 * 128 + i);
    for (int i = tid * 4; i < 32 * U_; i += 1024)
        *(float4*)&sh_x[i] = *(const float4*)(q_status + (size_t)row0 * U_ + i);
    __syncthreads();

    const int rg = tid >> 5;
    const int jg = tid & 31;
    float acc[4][4];
#pragma unroll
    for (int i = 0; i < 4; ++i)
#pragma unroll
        for (int j = 0; j < 4; ++j) acc[i][j] = 0.f;

    for (int k = 0; k < U_; ++k) {
        float4 w4 = *(float4*)&sh_w[k][jg * 4];
#pragma unroll
        for (int i = 0; i < 4; ++i) {
            float xv = sh_x[(rg * 4 + i) * U_ + k];
            acc[i][0] += xv * w4.x; acc[i][1] += xv * w4.y;
            acc[i][2] += xv * w4.z; acc[i][3] += xv * w4.w;
        }
    }
#pragma unroll
    for (int i = 0; i < 4; ++i) {
        int row = row0 + rg * 4 + i;
        float4 o = {acc[i][0], acc[i][1], acc[i][2], acc[i][3]};
        *(float4*)(QS1 + (size_t)row * U_ + jg * 4) = o;
    }
}

// ---------------------------------------------------------------------------
// K3: co[b] = qw[b] @ q_status[b]^T
// ---------------------------------------------------------------------------
__global__ __launch_bounds__(256) void k3_co(
    const float* __restrict__ qw,
    const float* __restrict__ q_status,
    float* __restrict__ co)
{
    __shared__ __align__(16) float sh_yT[U_][132];
    __shared__ __align__(16) float sh_x[32 * U_];

    const int tid = threadIdx.x;
    const int b = blockIdx.y;
    const int rt = blockIdx.x;

    const float* xs = qw + ((size_t)b * 320 + rt * 32) * U_;
    for (int i = tid * 4; i < 32 * U_; i += 1024)
        *(float4*)&sh_x[i] = *(const float4*)(xs + i);
    const float* ys = q_status + (size_t)b * 128 * U_;
    for (int i = tid; i < 128 * U_; i += 256) {
        int xn = i >> 7, v = i & 127;
        sh_yT[v][xn] = ys[i];
    }
    __syncthreads();

    const int rg = tid >> 5;
    const int cg = tid & 31;
    float acc[4][4];
#pragma unroll
    for (int i = 0; i < 4; ++i)
#pragma unroll
        for (int j = 0; j < 4; ++j) acc[i][j] = 0.f;

    for (int k = 0; k < U_; ++k) {
        float4 y4 = *(float4*)&sh_yT[k][cg * 4];
#pragma unroll
        for (int i = 0; i < 4; ++i) {
            float xv = sh_x[(rg * 4 + i) * U_ + k];
            acc[i][0] += xv * y4.x; acc[i][1] += xv * y4.y;
            acc[i][2] += xv * y4.z; acc[i][3] += xv * y4.w;
        }
    }
#pragma unroll
    for (int i = 0; i < 4; ++i) {
        int row = rt * 32 + rg * 4 + i;
        float4 o = {acc[i][0], acc[i][1], acc[i][2], acc[i][3]};
        *(float4*)(co + ((size_t)b * 320 + row) * U_ + cg * 4) = o;
    }
}

// ---------------------------------------------------------------------------
// K4a: per (bw): softmax over x per (s,n) -> h1 = relu(A + p2.QS1) -> bf16.
// grid = 512 blocks per chunk (bw_off selects chunk). LDS ~67 KB -> 2 blk/CU.
// h1 rows local to the chunk: r = (bw - bw_off)*160 + s*8 + n.
// ---------------------------------------------------------------------------
__global__ __launch_bounds__(256) void k4a_h1(
    const float* __restrict__ co,    // [B][320][128]
    const float* __restrict__ QS1,   // [B][128][128]
    const float* __restrict__ A,     // [B*W*S][128]
    unsigned short* __restrict__ h1g,// chunk-local [512*160][128] bf16
    int bw_off)
{
    __shared__ __align__(16) float sh_qs1[U_ * U_];  // 64 KB [xn][u]
    __shared__ __align__(16) float sh_a[U_];
    __shared__ __align__(16) float sh_co[U_];
    __shared__ __align__(16) float sh_p2[U_];        // [x][n]

    const int bw = blockIdx.x + bw_off;
    const int b = bw >> 4;
    const int tid = threadIdx.x;

    const float* qs1b = QS1 + (size_t)b * U_ * U_;
    for (int i = tid * 4; i < U_ * U_; i += 1024)
        *(float4*)&sh_qs1[i] = *(const float4*)&qs1b[i];

    const int n = tid >> 5;    // 0..7
    const int ug = tid & 31;   // u group of 4

    for (int s = 0; s < S_; ++s) {
        __syncthreads();   // protect sh_a/sh_co/sh_p2 (and sh_qs1 staging at s=0)
        const int rowbase = (bw * S_ + s) * U_;
        if (tid < 128) {
            sh_a[tid] = A[rowbase + tid];
            sh_co[tid] = co[rowbase + tid];
        }
        __syncthreads();

        if (tid < 64) {
            int nn = tid & 7, x0 = tid >> 3;
            float v0 = sh_co[x0 * 8 + nn];
            float v1 = sh_co[(x0 + 8) * 8 + nn];
            if (v0 == 0.0f) v0 = -INF_;
            if (v1 == 0.0f) v1 = -INF_;
            float m = fmaxf(v0, v1);
            m = fmaxf(m, __shfl_xor(m, 8));
            m = fmaxf(m, __shfl_xor(m, 16));
            m = fmaxf(m, __shfl_xor(m, 32));
            float e0 = expf(v0 - m), e1 = expf(v1 - m);
            float sm = e0 + e1;
            sm += __shfl_xor(sm, 8);
            sm += __shfl_xor(sm, 16);
            sm += __shfl_xor(sm, 32);
            float r = 1.0f / sm;
            sh_p2[x0 * 8 + nn] = e0 * r;
            sh_p2[(x0 + 8) * 8 + nn] = e1 * r;
        }
        __syncthreads();

        // h1[n][u0..u0+3] = relu(A + sum_x p2[x,n]*QS1[x*8+n][u])
        float4 acc = *(float4*)&sh_a[ug * 4];
#pragma unroll
        for (int x = 0; x < 16; ++x) {
            float pv = sh_p2[x * 8 + n];
            float4 q = *(float4*)&sh_qs1[(x * 8 + n) * U_ + ug * 4];
            acc.x += pv * q.x; acc.y += pv * q.y;
            acc.z += pv * q.z; acc.w += pv * q.w;
        }
        ushort4 o;
        o.x = f2bf(fmaxf(acc.x, 0.f));
        o.y = f2bf(fmaxf(acc.y, 0.f));
        o.z = f2bf(fmaxf(acc.z, 0.f));
        o.w = f2bf(fmaxf(acc.w, 0.f));
        size_t r = ((size_t)blockIdx.x * 160 + s * 8 + n) * U_ + ug * 4;
        *(ushort4*)(h1g + r) = o;
    }
}

// ---------------------------------------------------------------------------
// K4b: logits = relu(relu(h1@W2+b2))@W3 + b3 via bf16 MFMA 16x16x32.
// grid = 320 blocks per chunk; block = 256 rows x 128 cols.
// W2 converted+transposed to bf16 in LDS ([j][k], stride 136 shorts).
// ---------------------------------------------------------------------------
__global__ __launch_bounds__(256, 2) void k4b_mlp(
    const unsigned short* __restrict__ h1g,  // chunk-local [81920][128] bf16
    const float* __restrict__ W2,            // [128][128] fp32 (k-major rows)
    const float* __restrict__ b2,
    const float* __restrict__ W3,
    const float* __restrict__ b3,
    float* __restrict__ lgc)                 // chunk-local [81920]
{
    __shared__ __align__(16) unsigned short sh_w2t[U_ * 136];  // [j][k] 34816 B

    const int tid = threadIdx.x;
    // stage W2^T as bf16: sh_w2t[j*136+k] = bf16(W2[k*128+j])
    for (int i = tid; i < U_ * U_; i += 256) {
        int k = i >> 7, j = i & 127;
        sh_w2t[j * 136 + k] = f2bf(W2[i]);
    }
    __syncthreads();

    const int wave = tid >> 6, lane = tid & 63;
    const int m16 = lane & 15;   // row within mtile (A), col within jtile (B/D)
    const int q = lane >> 4;     // k-quad / row-quad

    const size_t row0 = (size_t)blockIdx.x * 256 + wave * 64;

    floatx4 acc[4][8];
#pragma unroll
    for (int mt = 0; mt < 4; ++mt)
#pragma unroll
        for (int jt = 0; jt < 8; ++jt) acc[mt][jt] = (floatx4)0.f;

#pragma unroll
    for (int kt = 0; kt < 4; ++kt) {
        const int k0 = kt * 32 + q * 8;
        bf16x8 af[4];
#pragma unroll
        for (int mt = 0; mt < 4; ++mt)
            af[mt] = *(const bf16x8*)(h1g + (row0 + mt * 16 + m16) * U_ + k0);
        bf16x8 bf[8];
#pragma unroll
        for (int jt = 0; jt < 8; ++jt)
            bf[jt] = *(const bf16x8*)(sh_w2t + (jt * 16 + m16) * 136 + k0);
#pragma unroll
        for (int mt = 0; mt < 4; ++mt)
#pragma unroll
            for (int jt = 0; jt < 8; ++jt)
                acc[mt][jt] = __builtin_amdgcn_mfma_f32_16x16x32_bf16(
                    af[mt], bf[jt], acc[mt][jt], 0, 0, 0);
    }

    // epilogue: h2 = relu(acc + b2), partial = h2 . W3 over this lane's col
    float b2v[8], w3v[8];
#pragma unroll
    for (int jt = 0; jt < 8; ++jt) {
        b2v[jt] = b2[jt * 16 + m16];
        w3v[jt] = W3[jt * 16 + m16];
    }
    const float b3v = b3[0];

#pragma unroll
    for (int mt = 0; mt < 4; ++mt) {
#pragma unroll
        for (int reg = 0; reg < 4; ++reg) {
            float p = 0.f;
#pragma unroll
            for (int jt = 0; jt < 8; ++jt)
                p += fmaxf(acc[mt][jt][reg] + b2v[jt], 0.f) * w3v[jt];
            p += __shfl_xor(p, 1);
            p += __shfl_xor(p, 2);
            p += __shfl_xor(p, 4);
            p += __shfl_xor(p, 8);
            if (m16 == 0)
                lgc[row0 + mt * 16 + q * 4 + reg] = p + b3v;
        }
    }
}

// ---------------------------------------------------------------------------
// K5: masked max over W, labels, scalar.
// ---------------------------------------------------------------------------
__global__ __launch_bounds__(256) void k5_final(
    const float* __restrict__ lg,
    const float* __restrict__ mask,
    float* __restrict__ out)
{
    int idx = blockIdx.x * 256 + threadIdx.x;
    const int SN = S_ * N_;
    if (idx < B_ * SN) {
        int b = idx / SN, sn = idx % SN;
        float m = -INFINITY;
        for (int w = 0; w < W_; ++w) {
            float v = lg[((size_t)b * W_ + w) * SN + sn] + mask[((size_t)b * W_ + w) * SN + sn];
            m = fmaxf(m, v);
        }
        out[idx] = (m > 0.f) ? 1.f : 0.f;
        out[B_ * SN + 1 + idx] = m;
    }
    if (idx == 0) out[B_ * SN] = (float)SN;
}

// ---------------------------------------------------------------------------
extern "C" void kernel_launch(void* const* d_in, const int* in_sizes, int n_in,
                              void* d_out, int out_size, void* d_ws, size_t ws_size,
                              hipStream_t stream) {
    const float* slot_utt_h = (const float*)d_in[0];
    const float* slot_candidate_c = (const float*)d_in[1];
    const float* position_encoding = (const float*)d_in[3];
    const float* q_status = (const float*)d_in[4];
    const float* mask = (const float*)d_in[5];
    const float* weight = (const float*)d_in[6];
    const float* W1 = (const float*)d_in[7];
    const float* b1 = (const float*)d_in[8];
    const float* W2 = (const float*)d_in[9];
    const float* b2 = (const float*)d_in[10];
    const float* W3 = (const float*)d_in[11];
    const float* b3 = (const float*)d_in[12];
    float* out = (float*)d_out;

    float* ws = (float*)d_ws;
    float* q_slot = ws;                  // 2,621,440 f
    float* qw     = q_slot + 2621440;    // 2,621,440 f
    float* A      = qw + 2621440;        // 2,621,440 f
    float* QS1    = A + 2621440;         // 1,048,576 f
    float* co     = QS1 + 1048576;       // 2,621,440 f
    float* lg     = co + 2621440;        //   163,840 f
    // h1 chunk buffer (bf16) overlays the dead q_slot+qw region:
    // 512 bw * 160 rows * 128 = 10,485,760 ushorts = 20.97 MB  (fits exactly)
    unsigned short* h1c = (unsigned short*)ws;

    k1_attn<<<B_ * W_, 256, 0, stream>>>(slot_utt_h, slot_candidate_c,
                                         position_encoding, q_slot);
    k2_qw_a<<<(B_ * W_ * S_) / 32, 256, 0, stream>>>(q_slot, weight, W1, b1, qw, A);
    k2_qs1<<<(B_ * W_ * N_) / 32, 256, 0, stream>>>(q_status, W1, QS1);
    k3_co<<<dim3(10, B_), 256, 0, stream>>>(qw, q_status, co);

    // two chunks of 512 bw each; h1c reuses q_slot+qw (dead after k3)
    for (int c = 0; c < 2; ++c) {
        k4a_h1<<<512, 256, 0, stream>>>(co, QS1, A, h1c, c * 512);
        k4b_mlp<<<320, 256, 0, stream>>>(h1c, W2, b2, W3, b3, lg + (size_t)c * 81920);
    }

    k5_final<<<(B_ * S_ * N_ + 255) / 256, 256, 0, stream>>>(lg, mask, out);
}

// Round 4
// 307.725 us; speedup vs baseline: 1.8589x; 1.0619x over previous
//
#include <hip/hip_runtime.h>
#include <math.h>

#define INF_ 100000.0f
constexpr int B_ = 64, W_ = 16, T_ = 64, U_ = 128, S_ = 20, N_ = 8;

typedef unsigned short ushort_t;
typedef __attribute__((ext_vector_type(8))) short bf16x8;
typedef __attribute__((ext_vector_type(4))) float floatx4;

static __device__ __forceinline__ unsigned short f2bf(float x) {
    unsigned int u = __float_as_uint(x);
    return (unsigned short)((u + 0x7fff + ((u >> 16) & 1)) >> 16);  // RNE
}
static __device__ __forceinline__ float bf2f(unsigned short s) {
    return __uint_as_float(((unsigned int)s) << 16);
}

// ---------------------------------------------------------------------------
// K0: cast/transpose prep.
// ---------------------------------------------------------------------------
__global__ __launch_bounds__(256) void k0_cast(
    const float* __restrict__ q_status, const float* __restrict__ weight,
    const float* __restrict__ W1, const float* __restrict__ W2,
    ushort_t* __restrict__ qstat_bf, ushort_t* __restrict__ wcomb,
    ushort_t* __restrict__ w1botT, ushort_t* __restrict__ w2T)
{
    int idx = blockIdx.x * 256 + threadIdx.x;
    if (idx < 1048576) { qstat_bf[idx] = f2bf(q_status[idx]); return; }
    idx -= 1048576;
    if (idx < 32768) {
        int j = idx >> 7, k = idx & 127;
        float v = (j < 128) ? weight[k * 128 + j] : W1[k * 128 + (j - 128)];
        wcomb[idx] = f2bf(v); return;
    }
    idx -= 32768;
    if (idx < 16384) {
        int j = idx >> 7, k = idx & 127;
        w1botT[idx] = f2bf(W1[(128 + k) * 128 + j]); return;
    }
    idx -= 16384;
    if (idx < 16384) {
        int j = idx >> 7, k = idx & 127;
        w2T[idx] = f2bf(W2[k * 128 + j]); return;
    }
}

// ---------------------------------------------------------------------------
// K1 (MFMA): per bw: sc = c@h^T -> softmax(t) -> q_slot = P@h + pos (bf16 out)
// ---------------------------------------------------------------------------
__global__ __launch_bounds__(256) void k1_attn(
    const float* __restrict__ h,    // [B,W,64,128]
    const float* __restrict__ c,    // [20,128]
    const float* __restrict__ pos,  // [B,W,20,128]
    ushort_t* __restrict__ q_slot_bf)  // [B*W*20][128]
{
    __shared__ __align__(16) ushort_t sh_h[64 * 136];    // [t][u]
    __shared__ __align__(16) ushort_t sh_hT[128 * 72];   // [u][t]
    __shared__ __align__(16) ushort_t sh_c[32 * 136];    // [s][u] (rows>=20 zero)
    __shared__ __align__(16) float    sh_sc[32 * 68];    // scores
    __shared__ __align__(16) ushort_t sh_P[32 * 72];     // [s][t] (rows>=20 zero)

    const int bw = blockIdx.x, tid = threadIdx.x;
    const float* hb = h + (size_t)bw * 8192;
    for (int i = tid; i < 8192; i += 256) {
        int t = i >> 7, u = i & 127;
        ushort_t v = f2bf(hb[i]);
        sh_h[t * 136 + u] = v;
        sh_hT[u * 72 + t] = v;
    }
    for (int i = tid; i < 4096; i += 256) {
        int s = i >> 7;
        sh_c[s * 136 + (i & 127)] = (s < 20) ? f2bf(c[i]) : (ushort_t)0;
    }
    for (int i = tid; i < 32 * 72; i += 256) sh_P[i] = 0;
    __syncthreads();

    const int wave = tid >> 6, lane = tid & 63, m16 = lane & 15, q = lane >> 4;

    // GEMM1: sc[s][t]: 2 mt x 4 jt, wave does 2 combos
#pragma unroll
    for (int ci = 0; ci < 2; ++ci) {
        int cmb = wave * 2 + ci;
        int mt = cmb >> 2, jt = cmb & 3;
        floatx4 acc = {0.f, 0.f, 0.f, 0.f};
#pragma unroll
        for (int kt = 0; kt < 4; ++kt) {
            bf16x8 a = *(const bf16x8*)&sh_c[(mt * 16 + m16) * 136 + kt * 32 + q * 8];
            bf16x8 b = *(const bf16x8*)&sh_h[(jt * 16 + m16) * 136 + kt * 32 + q * 8];
            acc = __builtin_amdgcn_mfma_f32_16x16x32_bf16(a, b, acc, 0, 0, 0);
        }
#pragma unroll
        for (int reg = 0; reg < 4; ++reg)
            sh_sc[(mt * 16 + q * 4 + reg) * 68 + jt * 16 + m16] = acc[reg];
    }
    __syncthreads();

    // softmax over t (wave per row)
    for (int s = wave; s < 20; s += 4) {
        float v = sh_sc[s * 68 + lane];
        if (v == 0.0f) v = -INF_;
        float m = v;
        for (int d = 32; d; d >>= 1) m = fmaxf(m, __shfl_xor(m, d));
        float e = expf(v - m);
        float sum = e;
        for (int d = 32; d; d >>= 1) sum += __shfl_xor(sum, d);
        sh_P[s * 72 + lane] = f2bf(e / sum);
    }
    __syncthreads();

    // GEMM2: q_slot = P@h + pos
    const size_t obase = (size_t)bw * 2560;
#pragma unroll
    for (int ci = 0; ci < 4; ++ci) {
        int cmb = wave * 4 + ci;
        int mt = cmb >> 3, jt = cmb & 7;
        floatx4 acc = {0.f, 0.f, 0.f, 0.f};
#pragma unroll
        for (int kt = 0; kt < 2; ++kt) {
            bf16x8 a = *(const bf16x8*)&sh_P[(mt * 16 + m16) * 72 + kt * 32 + q * 8];
            bf16x8 b = *(const bf16x8*)&sh_hT[(jt * 16 + m16) * 72 + kt * 32 + q * 8];
            acc = __builtin_amdgcn_mfma_f32_16x16x32_bf16(a, b, acc, 0, 0, 0);
        }
        int u = jt * 16 + m16;
#pragma unroll
        for (int reg = 0; reg < 4; ++reg) {
            int row = mt * 16 + q * 4 + reg;
            if (row < 20)
                q_slot_bf[obase + row * 128 + u] =
                    f2bf(acc[reg] + pos[obase + row * 128 + u]);
        }
    }
}

// ---------------------------------------------------------------------------
// K2a (MFMA): [qw_bf | A] = q_slot_bf @ wcomb.  320 blocks x 64 rows.
// ---------------------------------------------------------------------------
__global__ __launch_bounds__(256) void k2a(
    const ushort_t* __restrict__ qs_bf,  // [20480][128]
    const ushort_t* __restrict__ wcomb,  // [256][128] (j-major)
    const float* __restrict__ b1,
    ushort_t* __restrict__ qw_bf,        // [20480][128]
    float* __restrict__ A)               // [20480][128]
{
    __shared__ __align__(16) ushort_t sh_w[256 * 136];
    const int tid = threadIdx.x;
    for (int i = tid * 4; i < 32768; i += 1024) {
        int j = i >> 7, k = i & 127;
        *(ushort4*)&sh_w[j * 136 + k] = *(const ushort4*)&wcomb[i];
    }
    __syncthreads();

    const int wave = tid >> 6, lane = tid & 63, m16 = lane & 15, q = lane >> 4;
    const size_t row = (size_t)blockIdx.x * 64 + wave * 16 + m16;

    floatx4 acc[16];
#pragma unroll
    for (int jt = 0; jt < 16; ++jt) acc[jt] = (floatx4){0.f, 0.f, 0.f, 0.f};

#pragma unroll
    for (int kt = 0; kt < 4; ++kt) {
        bf16x8 a = *(const bf16x8*)&qs_bf[row * 128 + kt * 32 + q * 8];
#pragma unroll
        for (int jt = 0; jt < 16; ++jt) {
            bf16x8 b = *(const bf16x8*)&sh_w[(jt * 16 + m16) * 136 + kt * 32 + q * 8];
            acc[jt] = __builtin_amdgcn_mfma_f32_16x16x32_bf16(a, b, acc[jt], 0, 0, 0);
        }
    }

    const size_t orow0 = (size_t)blockIdx.x * 64 + wave * 16 + q * 4;
#pragma unroll
    for (int jt = 0; jt < 16; ++jt) {
        int col = jt * 16 + m16;
        if (col < 128) {
#pragma unroll
            for (int reg = 0; reg < 4; ++reg)
                qw_bf[(orow0 + reg) * 128 + col] = f2bf(acc[jt][reg]);
        } else {
            float bv = b1[col - 128];
#pragma unroll
            for (int reg = 0; reg < 4; ++reg)
                A[(orow0 + reg) * 128 + (col - 128)] = acc[jt][reg] + bv;
        }
    }
}

// ---------------------------------------------------------------------------
// K2b (MFMA): QS1_bf = qstat_bf @ W1bot.  128 blocks x 64 rows.
// ---------------------------------------------------------------------------
__global__ __launch_bounds__(256) void k2b(
    const ushort_t* __restrict__ qstat_bf,
    const ushort_t* __restrict__ w1botT,
    ushort_t* __restrict__ qs1_bf)
{
    __shared__ __align__(16) ushort_t sh_w[128 * 136];
    const int tid = threadIdx.x;
    for (int i = tid * 4; i < 16384; i += 1024) {
        int j = i >> 7, k = i & 127;
        *(ushort4*)&sh_w[j * 136 + k] = *(const ushort4*)&w1botT[i];
    }
    __syncthreads();

    const int wave = tid >> 6, lane = tid & 63, m16 = lane & 15, q = lane >> 4;
    const size_t row = (size_t)blockIdx.x * 64 + wave * 16 + m16;

    floatx4 acc[8];
#pragma unroll
    for (int jt = 0; jt < 8; ++jt) acc[jt] = (floatx4){0.f, 0.f, 0.f, 0.f};
#pragma unroll
    for (int kt = 0; kt < 4; ++kt) {
        bf16x8 a = *(const bf16x8*)&qstat_bf[row * 128 + kt * 32 + q * 8];
#pragma unroll
        for (int jt = 0; jt < 8; ++jt) {
            bf16x8 b = *(const bf16x8*)&sh_w[(jt * 16 + m16) * 136 + kt * 32 + q * 8];
            acc[jt] = __builtin_amdgcn_mfma_f32_16x16x32_bf16(a, b, acc[jt], 0, 0, 0);
        }
    }
    const size_t orow0 = (size_t)blockIdx.x * 64 + wave * 16 + q * 4;
#pragma unroll
    for (int jt = 0; jt < 8; ++jt) {
        int col = jt * 16 + m16;
#pragma unroll
        for (int reg = 0; reg < 4; ++reg)
            qs1_bf[(orow0 + reg) * 128 + col] = f2bf(acc[jt][reg]);
    }
}

// ---------------------------------------------------------------------------
// K3 (MFMA): co[b] = qw[b] @ qstat[b]^T (fp32 out).  grid (5, 64).
// ---------------------------------------------------------------------------
__global__ __launch_bounds__(256) void k3_co(
    const ushort_t* __restrict__ qw_bf,
    const ushort_t* __restrict__ qstat_bf,
    float* __restrict__ co)
{
    __shared__ __align__(16) ushort_t sh_y[128 * 136];
    const int tid = threadIdx.x, rt = blockIdx.x, b = blockIdx.y;
    for (int i = tid * 4; i < 16384; i += 1024) {
        int j = i >> 7, k = i & 127;
        *(ushort4*)&sh_y[j * 136 + k] = *(const ushort4*)&qstat_bf[(size_t)b * 16384 + i];
    }
    __syncthreads();

    const int wave = tid >> 6, lane = tid & 63, m16 = lane & 15, q = lane >> 4;
    const size_t rbase = (size_t)b * 320 + rt * 64 + wave * 16;

    floatx4 acc[8];
#pragma unroll
    for (int jt = 0; jt < 8; ++jt) acc[jt] = (floatx4){0.f, 0.f, 0.f, 0.f};
#pragma unroll
    for (int kt = 0; kt < 4; ++kt) {
        bf16x8 a = *(const bf16x8*)&qw_bf[(rbase + m16) * 128 + kt * 32 + q * 8];
#pragma unroll
        for (int jt = 0; jt < 8; ++jt) {
            bf16x8 b2_ = *(const bf16x8*)&sh_y[(jt * 16 + m16) * 136 + kt * 32 + q * 8];
            acc[jt] = __builtin_amdgcn_mfma_f32_16x16x32_bf16(a, b2_, acc[jt], 0, 0, 0);
        }
    }
#pragma unroll
    for (int jt = 0; jt < 8; ++jt)
#pragma unroll
        for (int reg = 0; reg < 4; ++reg)
            co[(rbase + q * 4 + reg) * 128 + jt * 16 + m16] = acc[jt][reg];
}

// ---------------------------------------------------------------------------
// K4 (fused, MFMA): per bw: softmax(x) -> h1 in A-frag registers -> h2 GEMM
// -> logits.  A is per-(bw,s): A[(bw*20+s)*128 + k]  (FIXED from R3).
// ---------------------------------------------------------------------------
__global__ __launch_bounds__(256, 2) void k4_fused(
    const float* __restrict__ co,        // [B][320][128]
    const ushort_t* __restrict__ qs1_bf, // [B][128][128]
    const float* __restrict__ A,         // [B*W*20][128]
    const ushort_t* __restrict__ w2T,    // [128][128] (j-major)
    const float* __restrict__ b2,
    const float* __restrict__ W3,
    const float* __restrict__ b3,
    float* __restrict__ lg)              // [B*W][160]
{
    __shared__ __align__(16) ushort_t sh_qs1[128 * 136];  // [xn][u]
    __shared__ __align__(16) ushort_t sh_w2t[128 * 136];  // [j][k]
    __shared__ __align__(16) float sh_p2[20 * 128];       // [s][x*8+n]

    const int bw = blockIdx.x, b = bw >> 4, tid = threadIdx.x;

    for (int i = tid * 4; i < 16384; i += 1024) {
        int r = i >> 7, k = i & 127;
        *(ushort4*)&sh_qs1[r * 136 + k] = *(const ushort4*)&qs1_bf[(size_t)b * 16384 + i];
        *(ushort4*)&sh_w2t[r * 136 + k] = *(const ushort4*)&w2T[i];
    }

    if (tid < 160) {
        int s = tid >> 3, n = tid & 7;
        const float* crow = co + ((size_t)bw * 20 + s) * 128;
        float v[16];
        float m = -INFINITY;
#pragma unroll
        for (int x = 0; x < 16; ++x) {
            float t = crow[x * 8 + n];
            if (t == 0.0f) t = -INF_;
            v[x] = t;
            m = fmaxf(m, t);
        }
        float sum = 0.f;
#pragma unroll
        for (int x = 0; x < 16; ++x) { v[x] = expf(v[x] - m); sum += v[x]; }
        float r = 1.0f / sum;
#pragma unroll
        for (int x = 0; x < 16; ++x) sh_p2[s * 128 + x * 8 + n] = v[x] * r;
    }
    __syncthreads();

    const int wave = tid >> 6, lane = tid & 63, m16 = lane & 15, q = lane >> 4;
    const int mt0 = (wave < 2) ? wave * 3 : 6 + (wave - 2) * 2;
    const int nmt = (wave < 2) ? 3 : 2;

    floatx4 acc[3][8];
#pragma unroll
    for (int mi = 0; mi < 3; ++mi)
#pragma unroll
        for (int jt = 0; jt < 8; ++jt) acc[mi][jt] = (floatx4){0.f, 0.f, 0.f, 0.f};

    const float* Ab = A + (size_t)bw * 20 * 128;   // 20 rows per bw (FIX)

    for (int kt = 0; kt < 4; ++kt) {
        const int k0 = kt * 32 + q * 8;
        bf16x8 bfr[8];
#pragma unroll
        for (int jt = 0; jt < 8; ++jt)
            bfr[jt] = *(const bf16x8*)&sh_w2t[(jt * 16 + m16) * 136 + k0];

        for (int mi = 0; mi < nmt; ++mi) {
            const int row = (mt0 + mi) * 16 + m16;   // 0..159 = s*8+n
            const int s = row >> 3, n = row & 7;
            float hv[8];
            const float* ar = Ab + s * 128 + k0;     // FIX: per-(bw,s) row
            float4 a0 = *(const float4*)ar;
            float4 a1 = *(const float4*)(ar + 4);
            hv[0] = a0.x; hv[1] = a0.y; hv[2] = a0.z; hv[3] = a0.w;
            hv[4] = a1.x; hv[5] = a1.y; hv[6] = a1.z; hv[7] = a1.w;
#pragma unroll
            for (int x = 0; x < 16; ++x) {
                float p = sh_p2[s * 128 + x * 8 + n];
                bf16x8 qv = *(const bf16x8*)&sh_qs1[(x * 8 + n) * 136 + k0];
                hv[0] += p * bf2f((ushort_t)qv[0]);
                hv[1] += p * bf2f((ushort_t)qv[1]);
                hv[2] += p * bf2f((ushort_t)qv[2]);
                hv[3] += p * bf2f((ushort_t)qv[3]);
                hv[4] += p * bf2f((ushort_t)qv[4]);
                hv[5] += p * bf2f((ushort_t)qv[5]);
                hv[6] += p * bf2f((ushort_t)qv[6]);
                hv[7] += p * bf2f((ushort_t)qv[7]);
            }
            bf16x8 af;
#pragma unroll
            for (int e = 0; e < 8; ++e) af[e] = (short)f2bf(fmaxf(hv[e], 0.f));
#pragma unroll
            for (int jt = 0; jt < 8; ++jt)
                acc[mi][jt] = __builtin_amdgcn_mfma_f32_16x16x32_bf16(
                    af, bfr[jt], acc[mi][jt], 0, 0, 0);
        }
    }

    float b2v[8], w3v[8];
#pragma unroll
    for (int jt = 0; jt < 8; ++jt) {
        b2v[jt] = b2[jt * 16 + m16];
        w3v[jt] = W3[jt * 16 + m16];
    }
    const float b3v = b3[0];

    for (int mi = 0; mi < nmt; ++mi) {
#pragma unroll
        for (int reg = 0; reg < 4; ++reg) {
            float p = 0.f;
#pragma unroll
            for (int jt = 0; jt < 8; ++jt)
                p += fmaxf(acc[mi][jt][reg] + b2v[jt], 0.f) * w3v[jt];
            p += __shfl_xor(p, 1);
            p += __shfl_xor(p, 2);
            p += __shfl_xor(p, 4);
            p += __shfl_xor(p, 8);
            if (m16 == 0)
                lg[(size_t)bw * 160 + (mt0 + mi) * 16 + q * 4 + reg] = p + b3v;
        }
    }
}

// ---------------------------------------------------------------------------
// K5: masked max over W, labels, scalar.
// ---------------------------------------------------------------------------
__global__ __launch_bounds__(256) void k5_final(
    const float* __restrict__ lg,
    const float* __restrict__ mask,
    float* __restrict__ out)
{
    int idx = blockIdx.x * 256 + threadIdx.x;
    const int SN = S_ * N_;
    if (idx < B_ * SN) {
        int b = idx / SN, sn = idx % SN;
        float m = -INFINITY;
        for (int w = 0; w < W_; ++w) {
            float v = lg[((size_t)b * W_ + w) * SN + sn] + mask[((size_t)b * W_ + w) * SN + sn];
            m = fmaxf(m, v);
        }
        out[idx] = (m > 0.f) ? 1.f : 0.f;
        out[B_ * SN + 1 + idx] = m;
    }
    if (idx == 0) out[B_ * SN] = (float)SN;
}

// ---------------------------------------------------------------------------
extern "C" void kernel_launch(void* const* d_in, const int* in_sizes, int n_in,
                              void* d_out, int out_size, void* d_ws, size_t ws_size,
                              hipStream_t stream) {
    const float* slot_utt_h = (const float*)d_in[0];
    const float* slot_candidate_c = (const float*)d_in[1];
    const float* position_encoding = (const float*)d_in[3];
    const float* q_status = (const float*)d_in[4];
    const float* mask = (const float*)d_in[5];
    const float* weight = (const float*)d_in[6];
    const float* W1 = (const float*)d_in[7];
    const float* b1 = (const float*)d_in[8];
    const float* W2 = (const float*)d_in[9];
    const float* b2 = (const float*)d_in[10];
    const float* W3 = (const float*)d_in[11];
    const float* b3 = (const float*)d_in[12];
    float* out = (float*)d_out;

    float* f = (float*)d_ws;
    ushort_t* q_slot_bf = (ushort_t*)(f + 0);        // 2,621,440 sh
    ushort_t* qw_bf     = (ushort_t*)(f + 1310720);  // 2,621,440 sh
    float*    A         = f + 2621440;               // 2,621,440 f
    ushort_t* qs1_bf    = (ushort_t*)(f + 5242880);  // 1,048,576 sh
    float*    co        = f + 5767168;               // 2,621,440 f
    float*    lg        = f + 8388608;               //   163,840 f
    ushort_t* qstat_bf  = (ushort_t*)(f + 8552448);  // 1,048,576 sh
    ushort_t* wcomb     = (ushort_t*)(f + 9076736);  //    32,768 sh
    ushort_t* w1botT    = (ushort_t*)(f + 9093120);  //    16,384 sh
    ushort_t* w2T       = (ushort_t*)(f + 9101312);  //    16,384 sh

    k0_cast<<<4352, 256, 0, stream>>>(q_status, weight, W1, W2,
                                      qstat_bf, wcomb, w1botT, w2T);
    k1_attn<<<1024, 256, 0, stream>>>(slot_utt_h, slot_candidate_c,
                                      position_encoding, q_slot_bf);
    k2b<<<128, 256, 0, stream>>>(qstat_bf, w1botT, qs1_bf);
    k2a<<<320, 256, 0, stream>>>(q_slot_bf, wcomb, b1, qw_bf, A);
    k3_co<<<dim3(5, 64), 256, 0, stream>>>(qw_bf, qstat_bf, co);
    k4_fused<<<1024, 256, 0, stream>>>(co, qs1_bf, A, w2T, b2, W3, b3, lg);
    k5_final<<<(B_ * S_ * N_ + 255) / 256, 256, 0, stream>>>(lg, mask, out);
}

// Round 5
// 265.727 us; speedup vs baseline: 2.1527x; 1.1580x over previous
//
#include <hip/hip_runtime.h>
#include <math.h>

#define INF_ 100000.0f
constexpr int B_ = 64, W_ = 16, T_ = 64, U_ = 128, S_ = 20, N_ = 8;

typedef unsigned short ushort_t;
typedef __attribute__((ext_vector_type(8))) short bf16x8;
typedef __attribute__((ext_vector_type(4))) float floatx4;

static __device__ __forceinline__ unsigned short f2bf(float x) {
    unsigned int u = __float_as_uint(x);
    return (unsigned short)((u + 0x7fff + ((u >> 16) & 1)) >> 16);  // RNE
}
static __device__ __forceinline__ float bf2f(unsigned short s) {
    return __uint_as_float(((unsigned int)s) << 16);
}

// ---------------------------------------------------------------------------
// K0: cast/transpose prep.
// ---------------------------------------------------------------------------
__global__ __launch_bounds__(256) void k0_cast(
    const float* __restrict__ q_status, const float* __restrict__ weight,
    const float* __restrict__ W1, const float* __restrict__ W2,
    ushort_t* __restrict__ qstat_bf, ushort_t* __restrict__ wcomb,
    ushort_t* __restrict__ w1botT, ushort_t* __restrict__ w2T)
{
    int idx = blockIdx.x * 256 + threadIdx.x;
    if (idx < 1048576) { qstat_bf[idx] = f2bf(q_status[idx]); return; }
    idx -= 1048576;
    if (idx < 32768) {
        int j = idx >> 7, k = idx & 127;
        float v = (j < 128) ? weight[k * 128 + j] : W1[k * 128 + (j - 128)];
        wcomb[idx] = f2bf(v); return;
    }
    idx -= 32768;
    if (idx < 16384) {
        int j = idx >> 7, k = idx & 127;
        w1botT[idx] = f2bf(W1[(128 + k) * 128 + j]); return;
    }
    idx -= 16384;
    if (idx < 16384) {
        int j = idx >> 7, k = idx & 127;
        w2T[idx] = f2bf(W2[k * 128 + j]); return;
    }
}

// ---------------------------------------------------------------------------
// K1 (MFMA): per bw: sc = c@h^T -> softmax(t) -> q_slot = P@h + pos (bf16 out)
// ---------------------------------------------------------------------------
__global__ __launch_bounds__(256) void k1_attn(
    const float* __restrict__ h,    // [B,W,64,128]
    const float* __restrict__ c,    // [20,128]
    const float* __restrict__ pos,  // [B,W,20,128]
    ushort_t* __restrict__ q_slot_bf)  // [B*W*20][128]
{
    __shared__ __align__(16) ushort_t sh_h[64 * 136];    // [t][u]
    __shared__ __align__(16) ushort_t sh_hT[128 * 72];   // [u][t]
    __shared__ __align__(16) ushort_t sh_c[32 * 136];    // [s][u] (rows>=20 zero)
    __shared__ __align__(16) float    sh_sc[32 * 68];    // scores
    __shared__ __align__(16) ushort_t sh_P[32 * 72];     // [s][t] (rows>=20 zero)

    const int bw = blockIdx.x, tid = threadIdx.x;
    const float* hb = h + (size_t)bw * 8192;
    for (int i = tid; i < 8192; i += 256) {
        int t = i >> 7, u = i & 127;
        ushort_t v = f2bf(hb[i]);
        sh_h[t * 136 + u] = v;
        sh_hT[u * 72 + t] = v;
    }
    for (int i = tid; i < 4096; i += 256) {
        int s = i >> 7;
        sh_c[s * 136 + (i & 127)] = (s < 20) ? f2bf(c[i]) : (ushort_t)0;
    }
    for (int i = tid; i < 32 * 72; i += 256) sh_P[i] = 0;
    __syncthreads();

    const int wave = tid >> 6, lane = tid & 63, m16 = lane & 15, q = lane >> 4;

    // GEMM1: sc[s][t]: 2 mt x 4 jt, wave does 2 combos
#pragma unroll
    for (int ci = 0; ci < 2; ++ci) {
        int cmb = wave * 2 + ci;
        int mt = cmb >> 2, jt = cmb & 3;
        floatx4 acc = {0.f, 0.f, 0.f, 0.f};
#pragma unroll
        for (int kt = 0; kt < 4; ++kt) {
            bf16x8 a = *(const bf16x8*)&sh_c[(mt * 16 + m16) * 136 + kt * 32 + q * 8];
            bf16x8 b = *(const bf16x8*)&sh_h[(jt * 16 + m16) * 136 + kt * 32 + q * 8];
            acc = __builtin_amdgcn_mfma_f32_16x16x32_bf16(a, b, acc, 0, 0, 0);
        }
#pragma unroll
        for (int reg = 0; reg < 4; ++reg)
            sh_sc[(mt * 16 + q * 4 + reg) * 68 + jt * 16 + m16] = acc[reg];
    }
    __syncthreads();

    // softmax over t (wave per row)
    for (int s = wave; s < 20; s += 4) {
        float v = sh_sc[s * 68 + lane];
        if (v == 0.0f) v = -INF_;
        float m = v;
        for (int d = 32; d; d >>= 1) m = fmaxf(m, __shfl_xor(m, d));
        float e = expf(v - m);
        float sum = e;
        for (int d = 32; d; d >>= 1) sum += __shfl_xor(sum, d);
        sh_P[s * 72 + lane] = f2bf(e / sum);
    }
    __syncthreads();

    // GEMM2: q_slot = P@h + pos
    const size_t obase = (size_t)bw * 2560;
#pragma unroll
    for (int ci = 0; ci < 4; ++ci) {
        int cmb = wave * 4 + ci;
        int mt = cmb >> 3, jt = cmb & 7;
        floatx4 acc = {0.f, 0.f, 0.f, 0.f};
#pragma unroll
        for (int kt = 0; kt < 2; ++kt) {
            bf16x8 a = *(const bf16x8*)&sh_P[(mt * 16 + m16) * 72 + kt * 32 + q * 8];
            bf16x8 b = *(const bf16x8*)&sh_hT[(jt * 16 + m16) * 72 + kt * 32 + q * 8];
            acc = __builtin_amdgcn_mfma_f32_16x16x32_bf16(a, b, acc, 0, 0, 0);
        }
        int u = jt * 16 + m16;
#pragma unroll
        for (int reg = 0; reg < 4; ++reg) {
            int row = mt * 16 + q * 4 + reg;
            if (row < 20)
                q_slot_bf[obase + row * 128 + u] =
                    f2bf(acc[reg] + pos[obase + row * 128 + u]);
        }
    }
}

// ---------------------------------------------------------------------------
// K2a (MFMA): [qw_bf | A] = q_slot_bf @ wcomb.  320 blocks x 64 rows.
// ---------------------------------------------------------------------------
__global__ __launch_bounds__(256) void k2a(
    const ushort_t* __restrict__ qs_bf,  // [20480][128]
    const ushort_t* __restrict__ wcomb,  // [256][128] (j-major)
    const float* __restrict__ b1,
    ushort_t* __restrict__ qw_bf,        // [20480][128]
    float* __restrict__ A)               // [20480][128]
{
    __shared__ __align__(16) ushort_t sh_w[256 * 136];
    const int tid = threadIdx.x;
    for (int i = tid * 4; i < 32768; i += 1024) {
        int j = i >> 7, k = i & 127;
        *(ushort4*)&sh_w[j * 136 + k] = *(const ushort4*)&wcomb[i];
    }
    __syncthreads();

    const int wave = tid >> 6, lane = tid & 63, m16 = lane & 15, q = lane >> 4;
    const size_t row = (size_t)blockIdx.x * 64 + wave * 16 + m16;

    floatx4 acc[16];
#pragma unroll
    for (int jt = 0; jt < 16; ++jt) acc[jt] = (floatx4){0.f, 0.f, 0.f, 0.f};

#pragma unroll
    for (int kt = 0; kt < 4; ++kt) {
        bf16x8 a = *(const bf16x8*)&qs_bf[row * 128 + kt * 32 + q * 8];
#pragma unroll
        for (int jt = 0; jt < 16; ++jt) {
            bf16x8 b = *(const bf16x8*)&sh_w[(jt * 16 + m16) * 136 + kt * 32 + q * 8];
            acc[jt] = __builtin_amdgcn_mfma_f32_16x16x32_bf16(a, b, acc[jt], 0, 0, 0);
        }
    }

    const size_t orow0 = (size_t)blockIdx.x * 64 + wave * 16 + q * 4;
#pragma unroll
    for (int jt = 0; jt < 16; ++jt) {
        int col = jt * 16 + m16;
        if (col < 128) {
#pragma unroll
            for (int reg = 0; reg < 4; ++reg)
                qw_bf[(orow0 + reg) * 128 + col] = f2bf(acc[jt][reg]);
        } else {
            float bv = b1[col - 128];
#pragma unroll
            for (int reg = 0; reg < 4; ++reg)
                A[(orow0 + reg) * 128 + (col - 128)] = acc[jt][reg] + bv;
        }
    }
}

// ---------------------------------------------------------------------------
// K2b (MFMA): QS1_bf = qstat_bf @ W1bot.  128 blocks x 64 rows.
// ---------------------------------------------------------------------------
__global__ __launch_bounds__(256) void k2b(
    const ushort_t* __restrict__ qstat_bf,
    const ushort_t* __restrict__ w1botT,
    ushort_t* __restrict__ qs1_bf)
{
    __shared__ __align__(16) ushort_t sh_w[128 * 136];
    const int tid = threadIdx.x;
    for (int i = tid * 4; i < 16384; i += 1024) {
        int j = i >> 7, k = i & 127;
        *(ushort4*)&sh_w[j * 136 + k] = *(const ushort4*)&w1botT[i];
    }
    __syncthreads();

    const int wave = tid >> 6, lane = tid & 63, m16 = lane & 15, q = lane >> 4;
    const size_t row = (size_t)blockIdx.x * 64 + wave * 16 + m16;

    floatx4 acc[8];
#pragma unroll
    for (int jt = 0; jt < 8; ++jt) acc[jt] = (floatx4){0.f, 0.f, 0.f, 0.f};
#pragma unroll
    for (int kt = 0; kt < 4; ++kt) {
        bf16x8 a = *(const bf16x8*)&qstat_bf[row * 128 + kt * 32 + q * 8];
#pragma unroll
        for (int jt = 0; jt < 8; ++jt) {
            bf16x8 b = *(const bf16x8*)&sh_w[(jt * 16 + m16) * 136 + kt * 32 + q * 8];
            acc[jt] = __builtin_amdgcn_mfma_f32_16x16x32_bf16(a, b, acc[jt], 0, 0, 0);
        }
    }
    const size_t orow0 = (size_t)blockIdx.x * 64 + wave * 16 + q * 4;
#pragma unroll
    for (int jt = 0; jt < 8; ++jt) {
        int col = jt * 16 + m16;
#pragma unroll
        for (int reg = 0; reg < 4; ++reg)
            qs1_bf[(orow0 + reg) * 128 + col] = f2bf(acc[jt][reg]);
    }
}

// ---------------------------------------------------------------------------
// K3 (MFMA): co[b] = qw[b] @ qstat[b]^T (fp32 out).  grid (5, 64).
// ---------------------------------------------------------------------------
__global__ __launch_bounds__(256) void k3_co(
    const ushort_t* __restrict__ qw_bf,
    const ushort_t* __restrict__ qstat_bf,
    float* __restrict__ co)
{
    __shared__ __align__(16) ushort_t sh_y[128 * 136];
    const int tid = threadIdx.x, rt = blockIdx.x, b = blockIdx.y;
    for (int i = tid * 4; i < 16384; i += 1024) {
        int j = i >> 7, k = i & 127;
        *(ushort4*)&sh_y[j * 136 + k] = *(const ushort4*)&qstat_bf[(size_t)b * 16384 + i];
    }
    __syncthreads();

    const int wave = tid >> 6, lane = tid & 63, m16 = lane & 15, q = lane >> 4;
    const size_t rbase = (size_t)b * 320 + rt * 64 + wave * 16;

    floatx4 acc[8];
#pragma unroll
    for (int jt = 0; jt < 8; ++jt) acc[jt] = (floatx4){0.f, 0.f, 0.f, 0.f};
#pragma unroll
    for (int kt = 0; kt < 4; ++kt) {
        bf16x8 a = *(const bf16x8*)&qw_bf[(rbase + m16) * 128 + kt * 32 + q * 8];
#pragma unroll
        for (int jt = 0; jt < 8; ++jt) {
            bf16x8 b2_ = *(const bf16x8*)&sh_y[(jt * 16 + m16) * 136 + kt * 32 + q * 8];
            acc[jt] = __builtin_amdgcn_mfma_f32_16x16x32_bf16(a, b2_, acc[jt], 0, 0, 0);
        }
    }
#pragma unroll
    for (int jt = 0; jt < 8; ++jt)
#pragma unroll
        for (int reg = 0; reg < 4; ++reg)
            co[(rbase + q * 4 + reg) * 128 + jt * 16 + m16] = acc[jt][reg];
}

// ---------------------------------------------------------------------------
// K4 (fused, MFMA): per bw: softmax(x) -> h1 in A-frag registers -> h2 GEMM
// -> logits.  320 threads = 5 waves x EXACTLY 2 mtiles (compile-time bounds:
// R4's runtime-bounded mi loop forced acc[] into scratch -> 577 MB/dispatch
// of HBM spill traffic; this restructure keeps acc in registers).
// ---------------------------------------------------------------------------
__global__ __launch_bounds__(320, 2) void k4_fused(
    const float* __restrict__ co,        // [B][320][128]
    const ushort_t* __restrict__ qs1_bf, // [B][128][128]
    const float* __restrict__ A,         // [B*W*20][128]
    const ushort_t* __restrict__ w2T,    // [128][128] (j-major)
    const float* __restrict__ b2,
    const float* __restrict__ W3,
    const float* __restrict__ b3,
    float* __restrict__ lg)              // [B*W][160]
{
    __shared__ __align__(16) ushort_t sh_qs1[128 * 136];  // [xn][u]
    __shared__ __align__(16) ushort_t sh_w2t[128 * 136];  // [j][k]
    __shared__ __align__(16) float sh_p2[20 * 128];       // [s][x*8+n]

    const int bw = blockIdx.x, b = bw >> 4, tid = threadIdx.x;

    for (int i = tid * 4; i < 16384; i += 1280) {
        int r = i >> 7, k = i & 127;
        *(ushort4*)&sh_qs1[r * 136 + k] = *(const ushort4*)&qs1_bf[(size_t)b * 16384 + i];
        *(ushort4*)&sh_w2t[r * 136 + k] = *(const ushort4*)&w2T[i];
    }

    if (tid < 160) {
        int s = tid >> 3, n = tid & 7;
        const float* crow = co + ((size_t)bw * 20 + s) * 128;
        float v[16];
        float m = -INFINITY;
#pragma unroll
        for (int x = 0; x < 16; ++x) {
            float t = crow[x * 8 + n];
            if (t == 0.0f) t = -INF_;
            v[x] = t;
            m = fmaxf(m, t);
        }
        float sum = 0.f;
#pragma unroll
        for (int x = 0; x < 16; ++x) { v[x] = expf(v[x] - m); sum += v[x]; }
        float r = 1.0f / sum;
#pragma unroll
        for (int x = 0; x < 16; ++x) sh_p2[s * 128 + x * 8 + n] = v[x] * r;
    }
    __syncthreads();

    const int wave = tid >> 6, lane = tid & 63, m16 = lane & 15, q = lane >> 4;
    // wave w handles mtiles {2w, 2w+1} — compile-time trip counts everywhere
    floatx4 acc[2][8];
#pragma unroll
    for (int mi = 0; mi < 2; ++mi)
#pragma unroll
        for (int jt = 0; jt < 8; ++jt) acc[mi][jt] = (floatx4){0.f, 0.f, 0.f, 0.f};

    const float* Ab = A + (size_t)bw * 20 * 128;   // 20 rows per bw

#pragma unroll
    for (int kt = 0; kt < 4; ++kt) {
        const int k0 = kt * 32 + q * 8;
        bf16x8 bfr[8];
#pragma unroll
        for (int jt = 0; jt < 8; ++jt)
            bfr[jt] = *(const bf16x8*)&sh_w2t[(jt * 16 + m16) * 136 + k0];

#pragma unroll
        for (int mi = 0; mi < 2; ++mi) {
            const int row = (wave * 2 + mi) * 16 + m16;   // 0..159 = s*8+n
            const int s = row >> 3, n = row & 7;
            float hv[8];
            const float* ar = Ab + s * 128 + k0;          // per-(bw,s) row
            float4 a0 = *(const float4*)ar;
            float4 a1 = *(const float4*)(ar + 4);
            hv[0] = a0.x; hv[1] = a0.y; hv[2] = a0.z; hv[3] = a0.w;
            hv[4] = a1.x; hv[5] = a1.y; hv[6] = a1.z; hv[7] = a1.w;
#pragma unroll
            for (int x = 0; x < 16; ++x) {
                float p = sh_p2[s * 128 + x * 8 + n];
                bf16x8 qv = *(const bf16x8*)&sh_qs1[(x * 8 + n) * 136 + k0];
                hv[0] += p * bf2f((ushort_t)qv[0]);
                hv[1] += p * bf2f((ushort_t)qv[1]);
                hv[2] += p * bf2f((ushort_t)qv[2]);
                hv[3] += p * bf2f((ushort_t)qv[3]);
                hv[4] += p * bf2f((ushort_t)qv[4]);
                hv[5] += p * bf2f((ushort_t)qv[5]);
                hv[6] += p * bf2f((ushort_t)qv[6]);
                hv[7] += p * bf2f((ushort_t)qv[7]);
            }
            bf16x8 af;
#pragma unroll
            for (int e = 0; e < 8; ++e) af[e] = (short)f2bf(fmaxf(hv[e], 0.f));
#pragma unroll
            for (int jt = 0; jt < 8; ++jt)
                acc[mi][jt] = __builtin_amdgcn_mfma_f32_16x16x32_bf16(
                    af, bfr[jt], acc[mi][jt], 0, 0, 0);
        }
    }

    float b2v[8], w3v[8];
#pragma unroll
    for (int jt = 0; jt < 8; ++jt) {
        b2v[jt] = b2[jt * 16 + m16];
        w3v[jt] = W3[jt * 16 + m16];
    }
    const float b3v = b3[0];

#pragma unroll
    for (int mi = 0; mi < 2; ++mi) {
#pragma unroll
        for (int reg = 0; reg < 4; ++reg) {
            float p = 0.f;
#pragma unroll
            for (int jt = 0; jt < 8; ++jt)
                p += fmaxf(acc[mi][jt][reg] + b2v[jt], 0.f) * w3v[jt];
            p += __shfl_xor(p, 1);
            p += __shfl_xor(p, 2);
            p += __shfl_xor(p, 4);
            p += __shfl_xor(p, 8);
            if (m16 == 0)
                lg[(size_t)bw * 160 + (wave * 2 + mi) * 16 + q * 4 + reg] = p + b3v;
        }
    }
}

// ---------------------------------------------------------------------------
// K5: masked max over W, labels, scalar.
// ---------------------------------------------------------------------------
__global__ __launch_bounds__(256) void k5_final(
    const float* __restrict__ lg,
    const float* __restrict__ mask,
    float* __restrict__ out)
{
    int idx = blockIdx.x * 256 + threadIdx.x;
    const int SN = S_ * N_;
    if (idx < B_ * SN) {
        int b = idx / SN, sn = idx % SN;
        float m = -INFINITY;
        for (int w = 0; w < W_; ++w) {
            float v = lg[((size_t)b * W_ + w) * SN + sn] + mask[((size_t)b * W_ + w) * SN + sn];
            m = fmaxf(m, v);
        }
        out[idx] = (m > 0.f) ? 1.f : 0.f;
        out[B_ * SN + 1 + idx] = m;
    }
    if (idx == 0) out[B_ * SN] = (float)SN;
}

// ---------------------------------------------------------------------------
extern "C" void kernel_launch(void* const* d_in, const int* in_sizes, int n_in,
                              void* d_out, int out_size, void* d_ws, size_t ws_size,
                              hipStream_t stream) {
    const float* slot_utt_h = (const float*)d_in[0];
    const float* slot_candidate_c = (const float*)d_in[1];
    const float* position_encoding = (const float*)d_in[3];
    const float* q_status = (const float*)d_in[4];
    const float* mask = (const float*)d_in[5];
    const float* weight = (const float*)d_in[6];
    const float* W1 = (const float*)d_in[7];
    const float* b1 = (const float*)d_in[8];
    const float* W2 = (const float*)d_in[9];
    const float* b2 = (const float*)d_in[10];
    const float* W3 = (const float*)d_in[11];
    const float* b3 = (const float*)d_in[12];
    float* out = (float*)d_out;

    float* f = (float*)d_ws;
    ushort_t* q_slot_bf = (ushort_t*)(f + 0);        // 2,621,440 sh
    ushort_t* qw_bf     = (ushort_t*)(f + 1310720);  // 2,621,440 sh
    float*    A         = f + 2621440;               // 2,621,440 f
    ushort_t* qs1_bf    = (ushort_t*)(f + 5242880);  // 1,048,576 sh
    float*    co        = f + 5767168;               // 2,621,440 f
    float*    lg        = f + 8388608;               //   163,840 f
    ushort_t* qstat_bf  = (ushort_t*)(f + 8552448);  // 1,048,576 sh
    ushort_t* wcomb     = (ushort_t*)(f + 9076736);  //    32,768 sh
    ushort_t* w1botT    = (ushort_t*)(f + 9093120);  //    16,384 sh
    ushort_t* w2T       = (ushort_t*)(f + 9101312);  //    16,384 sh

    k0_cast<<<4352, 256, 0, stream>>>(q_status, weight, W1, W2,
                                      qstat_bf, wcomb, w1botT, w2T);
    k1_attn<<<1024, 256, 0, stream>>>(slot_utt_h, slot_candidate_c,
                                      position_encoding, q_slot_bf);
    k2b<<<128, 256, 0, stream>>>(qstat_bf, w1botT, qs1_bf);
    k2a<<<320, 256, 0, stream>>>(q_slot_bf, wcomb, b1, qw_bf, A);
    k3_co<<<dim3(5, 64), 256, 0, stream>>>(qw_bf, qstat_bf, co);
    k4_fused<<<1024, 320, 0, stream>>>(co, qs1_bf, A, w2T, b2, W3, b3, lg);
    k5_final<<<(B_ * S_ * N_ + 255) / 256, 256, 0, stream>>>(lg, mask, out);
}

// Round 6
// 211.490 us; speedup vs baseline: 2.7047x; 1.2565x over previous
//
#include <hip/hip_runtime.h>
#include <math.h>

#define INF_ 100000.0f
constexpr int B_ = 64, W_ = 16, T_ = 64, U_ = 128, S_ = 20, N_ = 8;

typedef unsigned short ushort_t;
typedef __attribute__((ext_vector_type(8))) short bf16x8;
typedef __attribute__((ext_vector_type(4))) float floatx4;

static __device__ __forceinline__ unsigned short f2bf(float x) {
    unsigned int u = __float_as_uint(x);
    return (unsigned short)((u + 0x7fff + ((u >> 16) & 1)) >> 16);  // RNE
}
static __device__ __forceinline__ float bf2f(unsigned short s) {
    return __uint_as_float(((unsigned int)s) << 16);
}

// ---------------------------------------------------------------------------
// K0: cast/transpose prep.
// ---------------------------------------------------------------------------
__global__ __launch_bounds__(256) void k0_cast(
    const float* __restrict__ q_status, const float* __restrict__ weight,
    const float* __restrict__ W1, const float* __restrict__ W2,
    ushort_t* __restrict__ qstat_bf, ushort_t* __restrict__ wcomb,
    ushort_t* __restrict__ w1botT, ushort_t* __restrict__ w2T)
{
    int idx = blockIdx.x * 256 + threadIdx.x;
    if (idx < 1048576) { qstat_bf[idx] = f2bf(q_status[idx]); return; }
    idx -= 1048576;
    if (idx < 32768) {
        int j = idx >> 7, k = idx & 127;
        float v = (j < 128) ? weight[k * 128 + j] : W1[k * 128 + (j - 128)];
        wcomb[idx] = f2bf(v); return;
    }
    idx -= 32768;
    if (idx < 16384) {
        int j = idx >> 7, k = idx & 127;
        w1botT[idx] = f2bf(W1[(128 + k) * 128 + j]); return;
    }
    idx -= 16384;
    if (idx < 16384) {
        int j = idx >> 7, k = idx & 127;
        w2T[idx] = f2bf(W2[k * 128 + j]); return;
    }
}

// ---------------------------------------------------------------------------
// K1 (MFMA): per bw: sc = c@h^T -> softmax(t) -> q_slot = P@h + pos (bf16 out)
// ---------------------------------------------------------------------------
__global__ __launch_bounds__(256) void k1_attn(
    const float* __restrict__ h,    // [B,W,64,128]
    const float* __restrict__ c,    // [20,128]
    const float* __restrict__ pos,  // [B,W,20,128]
    ushort_t* __restrict__ q_slot_bf)  // [B*W*20][128]
{
    __shared__ __align__(16) ushort_t sh_h[64 * 136];    // [t][u]
    __shared__ __align__(16) ushort_t sh_hT[128 * 72];   // [u][t]
    __shared__ __align__(16) ushort_t sh_c[32 * 136];    // [s][u] (rows>=20 zero)
    __shared__ __align__(16) float    sh_sc[32 * 68];    // scores
    __shared__ __align__(16) ushort_t sh_P[32 * 72];     // [s][t] (rows>=20 zero)

    const int bw = blockIdx.x, tid = threadIdx.x;
    const float* hb = h + (size_t)bw * 8192;
    for (int i = tid; i < 8192; i += 256) {
        int t = i >> 7, u = i & 127;
        ushort_t v = f2bf(hb[i]);
        sh_h[t * 136 + u] = v;
        sh_hT[u * 72 + t] = v;
    }
    for (int i = tid; i < 4096; i += 256) {
        int s = i >> 7;
        sh_c[s * 136 + (i & 127)] = (s < 20) ? f2bf(c[i]) : (ushort_t)0;
    }
    for (int i = tid; i < 32 * 72; i += 256) sh_P[i] = 0;
    __syncthreads();

    const int wave = tid >> 6, lane = tid & 63, m16 = lane & 15, q = lane >> 4;

    // GEMM1: sc[s][t]: 2 mt x 4 jt, wave does 2 combos
#pragma unroll
    for (int ci = 0; ci < 2; ++ci) {
        int cmb = wave * 2 + ci;
        int mt = cmb >> 2, jt = cmb & 3;
        floatx4 acc = {0.f, 0.f, 0.f, 0.f};
#pragma unroll
        for (int kt = 0; kt < 4; ++kt) {
            bf16x8 a = *(const bf16x8*)&sh_c[(mt * 16 + m16) * 136 + kt * 32 + q * 8];
            bf16x8 b = *(const bf16x8*)&sh_h[(jt * 16 + m16) * 136 + kt * 32 + q * 8];
            acc = __builtin_amdgcn_mfma_f32_16x16x32_bf16(a, b, acc, 0, 0, 0);
        }
#pragma unroll
        for (int reg = 0; reg < 4; ++reg)
            sh_sc[(mt * 16 + q * 4 + reg) * 68 + jt * 16 + m16] = acc[reg];
    }
    __syncthreads();

    // softmax over t (wave per row)
    for (int s = wave; s < 20; s += 4) {
        float v = sh_sc[s * 68 + lane];
        if (v == 0.0f) v = -INF_;
        float m = v;
        for (int d = 32; d; d >>= 1) m = fmaxf(m, __shfl_xor(m, d));
        float e = expf(v - m);
        float sum = e;
        for (int d = 32; d; d >>= 1) sum += __shfl_xor(sum, d);
        sh_P[s * 72 + lane] = f2bf(e / sum);
    }
    __syncthreads();

    // GEMM2: q_slot = P@h + pos
    const size_t obase = (size_t)bw * 2560;
#pragma unroll
    for (int ci = 0; ci < 4; ++ci) {
        int cmb = wave * 4 + ci;
        int mt = cmb >> 3, jt = cmb & 7;
        floatx4 acc = {0.f, 0.f, 0.f, 0.f};
#pragma unroll
        for (int kt = 0; kt < 2; ++kt) {
            bf16x8 a = *(const bf16x8*)&sh_P[(mt * 16 + m16) * 72 + kt * 32 + q * 8];
            bf16x8 b = *(const bf16x8*)&sh_hT[(jt * 16 + m16) * 72 + kt * 32 + q * 8];
            acc = __builtin_amdgcn_mfma_f32_16x16x32_bf16(a, b, acc, 0, 0, 0);
        }
        int u = jt * 16 + m16;
#pragma unroll
        for (int reg = 0; reg < 4; ++reg) {
            int row = mt * 16 + q * 4 + reg;
            if (row < 20)
                q_slot_bf[obase + row * 128 + u] =
                    f2bf(acc[reg] + pos[obase + row * 128 + u]);
        }
    }
}

// ---------------------------------------------------------------------------
// K2a (MFMA): [qw_bf | A] = q_slot_bf @ wcomb.  320 blocks x 64 rows.
// ---------------------------------------------------------------------------
__global__ __launch_bounds__(256) void k2a(
    const ushort_t* __restrict__ qs_bf,  // [20480][128]
    const ushort_t* __restrict__ wcomb,  // [256][128] (j-major)
    const float* __restrict__ b1,
    ushort_t* __restrict__ qw_bf,        // [20480][128]
    float* __restrict__ A)               // [20480][128]
{
    __shared__ __align__(16) ushort_t sh_w[256 * 136];
    const int tid = threadIdx.x;
    for (int i = tid * 4; i < 32768; i += 1024) {
        int j = i >> 7, k = i & 127;
        *(ushort4*)&sh_w[j * 136 + k] = *(const ushort4*)&wcomb[i];
    }
    __syncthreads();

    const int wave = tid >> 6, lane = tid & 63, m16 = lane & 15, q = lane >> 4;
    const size_t row = (size_t)blockIdx.x * 64 + wave * 16 + m16;

    floatx4 acc[16];
#pragma unroll
    for (int jt = 0; jt < 16; ++jt) acc[jt] = (floatx4){0.f, 0.f, 0.f, 0.f};

#pragma unroll
    for (int kt = 0; kt < 4; ++kt) {
        bf16x8 a = *(const bf16x8*)&qs_bf[row * 128 + kt * 32 + q * 8];
#pragma unroll
        for (int jt = 0; jt < 16; ++jt) {
            bf16x8 b = *(const bf16x8*)&sh_w[(jt * 16 + m16) * 136 + kt * 32 + q * 8];
            acc[jt] = __builtin_amdgcn_mfma_f32_16x16x32_bf16(a, b, acc[jt], 0, 0, 0);
        }
    }

    const size_t orow0 = (size_t)blockIdx.x * 64 + wave * 16 + q * 4;
#pragma unroll
    for (int jt = 0; jt < 16; ++jt) {
        int col = jt * 16 + m16;
        if (col < 128) {
#pragma unroll
            for (int reg = 0; reg < 4; ++reg)
                qw_bf[(orow0 + reg) * 128 + col] = f2bf(acc[jt][reg]);
        } else {
            float bv = b1[col - 128];
#pragma unroll
            for (int reg = 0; reg < 4; ++reg)
                A[(orow0 + reg) * 128 + (col - 128)] = acc[jt][reg] + bv;
        }
    }
}

// ---------------------------------------------------------------------------
// K2b (MFMA): QS1_bf = qstat_bf @ W1bot.  128 blocks x 64 rows.
// ---------------------------------------------------------------------------
__global__ __launch_bounds__(256) void k2b(
    const ushort_t* __restrict__ qstat_bf,
    const ushort_t* __restrict__ w1botT,
    ushort_t* __restrict__ qs1_bf)
{
    __shared__ __align__(16) ushort_t sh_w[128 * 136];
    const int tid = threadIdx.x;
    for (int i = tid * 4; i < 16384; i += 1024) {
        int j = i >> 7, k = i & 127;
        *(ushort4*)&sh_w[j * 136 + k] = *(const ushort4*)&w1botT[i];
    }
    __syncthreads();

    const int wave = tid >> 6, lane = tid & 63, m16 = lane & 15, q = lane >> 4;
    const size_t row = (size_t)blockIdx.x * 64 + wave * 16 + m16;

    floatx4 acc[8];
#pragma unroll
    for (int jt = 0; jt < 8; ++jt) acc[jt] = (floatx4){0.f, 0.f, 0.f, 0.f};
#pragma unroll
    for (int kt = 0; kt < 4; ++kt) {
        bf16x8 a = *(const bf16x8*)&qstat_bf[row * 128 + kt * 32 + q * 8];
#pragma unroll
        for (int jt = 0; jt < 8; ++jt) {
            bf16x8 b = *(const bf16x8*)&sh_w[(jt * 16 + m16) * 136 + kt * 32 + q * 8];
            acc[jt] = __builtin_amdgcn_mfma_f32_16x16x32_bf16(a, b, acc[jt], 0, 0, 0);
        }
    }
    const size_t orow0 = (size_t)blockIdx.x * 64 + wave * 16 + q * 4;
#pragma unroll
    for (int jt = 0; jt < 8; ++jt) {
        int col = jt * 16 + m16;
#pragma unroll
        for (int reg = 0; reg < 4; ++reg)
            qs1_bf[(orow0 + reg) * 128 + col] = f2bf(acc[jt][reg]);
    }
}

// ---------------------------------------------------------------------------
// K3 (MFMA): co[b] = qw[b] @ qstat[b]^T (fp32 out).  grid (5, 64).
// ---------------------------------------------------------------------------
__global__ __launch_bounds__(256) void k3_co(
    const ushort_t* __restrict__ qw_bf,
    const ushort_t* __restrict__ qstat_bf,
    float* __restrict__ co)
{
    __shared__ __align__(16) ushort_t sh_y[128 * 136];
    const int tid = threadIdx.x, rt = blockIdx.x, b = blockIdx.y;
    for (int i = tid * 4; i < 16384; i += 1024) {
        int j = i >> 7, k = i & 127;
        *(ushort4*)&sh_y[j * 136 + k] = *(const ushort4*)&qstat_bf[(size_t)b * 16384 + i];
    }
    __syncthreads();

    const int wave = tid >> 6, lane = tid & 63, m16 = lane & 15, q = lane >> 4;
    const size_t rbase = (size_t)b * 320 + rt * 64 + wave * 16;

    floatx4 acc[8];
#pragma unroll
    for (int jt = 0; jt < 8; ++jt) acc[jt] = (floatx4){0.f, 0.f, 0.f, 0.f};
#pragma unroll
    for (int kt = 0; kt < 4; ++kt) {
        bf16x8 a = *(const bf16x8*)&qw_bf[(rbase + m16) * 128 + kt * 32 + q * 8];
#pragma unroll
        for (int jt = 0; jt < 8; ++jt) {
            bf16x8 b2_ = *(const bf16x8*)&sh_y[(jt * 16 + m16) * 136 + kt * 32 + q * 8];
            acc[jt] = __builtin_amdgcn_mfma_f32_16x16x32_bf16(a, b2_, acc[jt], 0, 0, 0);
        }
    }
#pragma unroll
    for (int jt = 0; jt < 8; ++jt)
#pragma unroll
        for (int reg = 0; reg < 4; ++reg)
            co[(rbase + q * 4 + reg) * 128 + jt * 16 + m16] = acc[jt][reg];
}

// ---------------------------------------------------------------------------
// K4 (fused, MFMA): per bw: softmax(x) -> h1 in A-frag registers -> h2 GEMM
// -> logits.  640 threads = 10 waves x EXACTLY 1 mtile: acc[8] = 32 VGPRs,
// peak live ~110 regs (R5's acc[2][8]=64 + bfr[8]=32 + temps ~= 140 > the
// 128-reg cap -> 122 MB/dispatch scratch spill).  __launch_bounds__(640,3)
// caps VGPR at ~168 (also required: 10-wave block needs <=170/wave to fit
// 3 waves on an EU).
// ---------------------------------------------------------------------------
__global__ __launch_bounds__(640, 3) void k4_fused(
    const float* __restrict__ co,        // [B][320][128]
    const ushort_t* __restrict__ qs1_bf, // [B][128][128]
    const float* __restrict__ A,         // [B*W*20][128]
    const ushort_t* __restrict__ w2T,    // [128][128] (j-major)
    const float* __restrict__ b2,
    const float* __restrict__ W3,
    const float* __restrict__ b3,
    float* __restrict__ lg)              // [B*W][160]
{
    __shared__ __align__(16) ushort_t sh_qs1[128 * 136];  // [xn][u]
    __shared__ __align__(16) ushort_t sh_w2t[128 * 136];  // [j][k]
    __shared__ __align__(16) float sh_p2[20 * 128];       // [s][x*8+n]

    const int bw = blockIdx.x, b = bw >> 4, tid = threadIdx.x;

    for (int i = tid * 4; i < 16384; i += 2560) {
        int r = i >> 7, k = i & 127;
        *(ushort4*)&sh_qs1[r * 136 + k] = *(const ushort4*)&qs1_bf[(size_t)b * 16384 + i];
        *(ushort4*)&sh_w2t[r * 136 + k] = *(const ushort4*)&w2T[i];
    }

    if (tid < 160) {
        int s = tid >> 3, n = tid & 7;
        const float* crow = co + ((size_t)bw * 20 + s) * 128;
        float v[16];
        float m = -INFINITY;
#pragma unroll
        for (int x = 0; x < 16; ++x) {
            float t = crow[x * 8 + n];
            if (t == 0.0f) t = -INF_;
            v[x] = t;
            m = fmaxf(m, t);
        }
        float sum = 0.f;
#pragma unroll
        for (int x = 0; x < 16; ++x) { v[x] = expf(v[x] - m); sum += v[x]; }
        float r = 1.0f / sum;
#pragma unroll
        for (int x = 0; x < 16; ++x) sh_p2[s * 128 + x * 8 + n] = v[x] * r;
    }
    __syncthreads();

    const int wave = tid >> 6, lane = tid & 63, m16 = lane & 15, q = lane >> 4;
    const int row = wave * 16 + m16;   // 0..159 = s*8+n  (one mtile per wave)
    const int s = row >> 3, n = row & 7;

    floatx4 acc[8];
#pragma unroll
    for (int jt = 0; jt < 8; ++jt) acc[jt] = (floatx4){0.f, 0.f, 0.f, 0.f};

    const float* Ab = A + (size_t)bw * 20 * 128;   // 20 rows per bw

#pragma unroll
    for (int kt = 0; kt < 4; ++kt) {
        const int k0 = kt * 32 + q * 8;
        bf16x8 bfr[8];
#pragma unroll
        for (int jt = 0; jt < 8; ++jt)
            bfr[jt] = *(const bf16x8*)&sh_w2t[(jt * 16 + m16) * 136 + k0];

        float hv[8];
        const float* ar = Ab + s * 128 + k0;       // per-(bw,s) row
        float4 a0 = *(const float4*)ar;
        float4 a1 = *(const float4*)(ar + 4);
        hv[0] = a0.x; hv[1] = a0.y; hv[2] = a0.z; hv[3] = a0.w;
        hv[4] = a1.x; hv[5] = a1.y; hv[6] = a1.z; hv[7] = a1.w;
#pragma unroll
        for (int x = 0; x < 16; ++x) {
            float p = sh_p2[s * 128 + x * 8 + n];
            bf16x8 qv = *(const bf16x8*)&sh_qs1[(x * 8 + n) * 136 + k0];
            hv[0] += p * bf2f((ushort_t)qv[0]);
            hv[1] += p * bf2f((ushort_t)qv[1]);
            hv[2] += p * bf2f((ushort_t)qv[2]);
            hv[3] += p * bf2f((ushort_t)qv[3]);
            hv[4] += p * bf2f((ushort_t)qv[4]);
            hv[5] += p * bf2f((ushort_t)qv[5]);
            hv[6] += p * bf2f((ushort_t)qv[6]);
            hv[7] += p * bf2f((ushort_t)qv[7]);
        }
        bf16x8 af;
#pragma unroll
        for (int e = 0; e < 8; ++e) af[e] = (short)f2bf(fmaxf(hv[e], 0.f));
#pragma unroll
        for (int jt = 0; jt < 8; ++jt)
            acc[jt] = __builtin_amdgcn_mfma_f32_16x16x32_bf16(
                af, bfr[jt], acc[jt], 0, 0, 0);
    }

    float b2v[8], w3v[8];
#pragma unroll
    for (int jt = 0; jt < 8; ++jt) {
        b2v[jt] = b2[jt * 16 + m16];
        w3v[jt] = W3[jt * 16 + m16];
    }
    const float b3v = b3[0];

#pragma unroll
    for (int reg = 0; reg < 4; ++reg) {
        float p = 0.f;
#pragma unroll
        for (int jt = 0; jt < 8; ++jt)
            p += fmaxf(acc[jt][reg] + b2v[jt], 0.f) * w3v[jt];
        p += __shfl_xor(p, 1);
        p += __shfl_xor(p, 2);
        p += __shfl_xor(p, 4);
        p += __shfl_xor(p, 8);
        if (m16 == 0)
            lg[(size_t)bw * 160 + wave * 16 + q * 4 + reg] = p + b3v;
    }
}

// ---------------------------------------------------------------------------
// K5: masked max over W, labels, scalar.
// ---------------------------------------------------------------------------
__global__ __launch_bounds__(256) void k5_final(
    const float* __restrict__ lg,
    const float* __restrict__ mask,
    float* __restrict__ out)
{
    int idx = blockIdx.x * 256 + threadIdx.x;
    const int SN = S_ * N_;
    if (idx < B_ * SN) {
        int b = idx / SN, sn = idx % SN;
        float m = -INFINITY;
        for (int w = 0; w < W_; ++w) {
            float v = lg[((size_t)b * W_ + w) * SN + sn] + mask[((size_t)b * W_ + w) * SN + sn];
            m = fmaxf(m, v);
        }
        out[idx] = (m > 0.f) ? 1.f : 0.f;
        out[B_ * SN + 1 + idx] = m;
    }
    if (idx == 0) out[B_ * SN] = (float)SN;
}

// ---------------------------------------------------------------------------
extern "C" void kernel_launch(void* const* d_in, const int* in_sizes, int n_in,
                              void* d_out, int out_size, void* d_ws, size_t ws_size,
                              hipStream_t stream) {
    const float* slot_utt_h = (const float*)d_in[0];
    const float* slot_candidate_c = (const float*)d_in[1];
    const float* position_encoding = (const float*)d_in[3];
    const float* q_status = (const float*)d_in[4];
    const float* mask = (const float*)d_in[5];
    const float* weight = (const float*)d_in[6];
    const float* W1 = (const float*)d_in[7];
    const float* b1 = (const float*)d_in[8];
    const float* W2 = (const float*)d_in[9];
    const float* b2 = (const float*)d_in[10];
    const float* W3 = (const float*)d_in[11];
    const float* b3 = (const float*)d_in[12];
    float* out = (float*)d_out;

    float* f = (float*)d_ws;
    ushort_t* q_slot_bf = (ushort_t*)(f + 0);        // 2,621,440 sh
    ushort_t* qw_bf     = (ushort_t*)(f + 1310720);  // 2,621,440 sh
    float*    A         = f + 2621440;               // 2,621,440 f
    ushort_t* qs1_bf    = (ushort_t*)(f + 5242880);  // 1,048,576 sh
    float*    co        = f + 5767168;               // 2,621,440 f
    float*    lg        = f + 8388608;               //   163,840 f
    ushort_t* qstat_bf  = (ushort_t*)(f + 8552448);  // 1,048,576 sh
    ushort_t* wcomb     = (ushort_t*)(f + 9076736);  //    32,768 sh
    ushort_t* w1botT    = (ushort_t*)(f + 9093120);  //    16,384 sh
    ushort_t* w2T       = (ushort_t*)(f + 9101312);  //    16,384 sh

    k0_cast<<<4352, 256, 0, stream>>>(q_status, weight, W1, W2,
                                      qstat_bf, wcomb, w1botT, w2T);
    k1_attn<<<1024, 256, 0, stream>>>(slot_utt_h, slot_candidate_c,
                                      position_encoding, q_slot_bf);
    k2b<<<128, 256, 0, stream>>>(qstat_bf, w1botT, qs1_bf);
    k2a<<<320, 256, 0, stream>>>(q_slot_bf, wcomb, b1, qw_bf, A);
    k3_co<<<dim3(5, 64), 256, 0, stream>>>(qw_bf, qstat_bf, co);
    k4_fused<<<1024, 640, 0, stream>>>(co, qs1_bf, A, w2T, b2, W3, b3, lg);
    k5_final<<<(B_ * S_ * N_ + 255) / 256, 256, 0, stream>>>(lg, mask, out);
}

// Round 7
// 199.176 us; speedup vs baseline: 2.8719x; 1.0618x over previous
//
#include <hip/hip_runtime.h>
#include <math.h>

#define INF_ 100000.0f
constexpr int B_ = 64, W_ = 16, T_ = 64, U_ = 128, S_ = 20, N_ = 8;

typedef unsigned short ushort_t;
typedef __attribute__((ext_vector_type(8))) short bf16x8;
typedef __attribute__((ext_vector_type(4))) float floatx4;

static __device__ __forceinline__ unsigned short f2bf(float x) {
    unsigned int u = __float_as_uint(x);
    return (unsigned short)((u + 0x7fff + ((u >> 16) & 1)) >> 16);  // RNE
}

// ---------------------------------------------------------------------------
// K0: cast/transpose prep.
// ---------------------------------------------------------------------------
__global__ __launch_bounds__(256) void k0_cast(
    const float* __restrict__ q_status, const float* __restrict__ weight,
    const float* __restrict__ W1, const float* __restrict__ W2,
    ushort_t* __restrict__ qstat_bf, ushort_t* __restrict__ wcomb,
    ushort_t* __restrict__ w1botT, ushort_t* __restrict__ w2T)
{
    int idx = blockIdx.x * 256 + threadIdx.x;
    if (idx < 1048576) { qstat_bf[idx] = f2bf(q_status[idx]); return; }
    idx -= 1048576;
    if (idx < 32768) {
        int j = idx >> 7, k = idx & 127;
        float v = (j < 128) ? weight[k * 128 + j] : W1[k * 128 + (j - 128)];
        wcomb[idx] = f2bf(v); return;
    }
    idx -= 32768;
    if (idx < 16384) {
        int j = idx >> 7, k = idx & 127;
        w1botT[idx] = f2bf(W1[(128 + k) * 128 + j]); return;
    }
    idx -= 16384;
    if (idx < 16384) {
        int j = idx >> 7, k = idx & 127;
        w2T[idx] = f2bf(W2[k * 128 + j]); return;
    }
}

// ---------------------------------------------------------------------------
// K1 (MFMA): per bw: sc = c@h^T -> softmax(t) -> q_slot = P@h + pos (bf16 out)
// ---------------------------------------------------------------------------
__global__ __launch_bounds__(256) void k1_attn(
    const float* __restrict__ h,    // [B,W,64,128]
    const float* __restrict__ c,    // [20,128]
    const float* __restrict__ pos,  // [B,W,20,128]
    ushort_t* __restrict__ q_slot_bf)  // [B*W*20][128]
{
    __shared__ __align__(16) ushort_t sh_h[64 * 136];    // [t][u]
    __shared__ __align__(16) ushort_t sh_hT[128 * 72];   // [u][t]
    __shared__ __align__(16) ushort_t sh_c[32 * 136];    // [s][u] (rows>=20 zero)
    __shared__ __align__(16) float    sh_sc[32 * 68];    // scores
    __shared__ __align__(16) ushort_t sh_P[32 * 72];     // [s][t] (rows>=20 zero)

    const int bw = blockIdx.x, tid = threadIdx.x;
    const float* hb = h + (size_t)bw * 8192;
    for (int i = tid; i < 8192; i += 256) {
        int t = i >> 7, u = i & 127;
        ushort_t v = f2bf(hb[i]);
        sh_h[t * 136 + u] = v;
        sh_hT[u * 72 + t] = v;
    }
    for (int i = tid; i < 4096; i += 256) {
        int s = i >> 7;
        sh_c[s * 136 + (i & 127)] = (s < 20) ? f2bf(c[i]) : (ushort_t)0;
    }
    for (int i = tid; i < 32 * 72; i += 256) sh_P[i] = 0;
    __syncthreads();

    const int wave = tid >> 6, lane = tid & 63, m16 = lane & 15, q = lane >> 4;

    // GEMM1: sc[s][t]: 2 mt x 4 jt, wave does 2 combos
#pragma unroll
    for (int ci = 0; ci < 2; ++ci) {
        int cmb = wave * 2 + ci;
        int mt = cmb >> 2, jt = cmb & 3;
        floatx4 acc = {0.f, 0.f, 0.f, 0.f};
#pragma unroll
        for (int kt = 0; kt < 4; ++kt) {
            bf16x8 a = *(const bf16x8*)&sh_c[(mt * 16 + m16) * 136 + kt * 32 + q * 8];
            bf16x8 b = *(const bf16x8*)&sh_h[(jt * 16 + m16) * 136 + kt * 32 + q * 8];
            acc = __builtin_amdgcn_mfma_f32_16x16x32_bf16(a, b, acc, 0, 0, 0);
        }
#pragma unroll
        for (int reg = 0; reg < 4; ++reg)
            sh_sc[(mt * 16 + q * 4 + reg) * 68 + jt * 16 + m16] = acc[reg];
    }
    __syncthreads();

    // softmax over t (wave per row)
    for (int s = wave; s < 20; s += 4) {
        float v = sh_sc[s * 68 + lane];
        if (v == 0.0f) v = -INF_;
        float m = v;
        for (int d = 32; d; d >>= 1) m = fmaxf(m, __shfl_xor(m, d));
        float e = expf(v - m);
        float sum = e;
        for (int d = 32; d; d >>= 1) sum += __shfl_xor(sum, d);
        sh_P[s * 72 + lane] = f2bf(e / sum);
    }
    __syncthreads();

    // GEMM2: q_slot = P@h + pos
    const size_t obase = (size_t)bw * 2560;
#pragma unroll
    for (int ci = 0; ci < 4; ++ci) {
        int cmb = wave * 4 + ci;
        int mt = cmb >> 3, jt = cmb & 7;
        floatx4 acc = {0.f, 0.f, 0.f, 0.f};
#pragma unroll
        for (int kt = 0; kt < 2; ++kt) {
            bf16x8 a = *(const bf16x8*)&sh_P[(mt * 16 + m16) * 72 + kt * 32 + q * 8];
            bf16x8 b = *(const bf16x8*)&sh_hT[(jt * 16 + m16) * 72 + kt * 32 + q * 8];
            acc = __builtin_amdgcn_mfma_f32_16x16x32_bf16(a, b, acc, 0, 0, 0);
        }
        int u = jt * 16 + m16;
#pragma unroll
        for (int reg = 0; reg < 4; ++reg) {
            int row = mt * 16 + q * 4 + reg;
            if (row < 20)
                q_slot_bf[obase + row * 128 + u] =
                    f2bf(acc[reg] + pos[obase + row * 128 + u]);
        }
    }
}

// ---------------------------------------------------------------------------
// K2a (MFMA): [qw_bf | A] = q_slot_bf @ wcomb.  160 blocks x 128 rows,
// 512 threads (8 waves): halves per-block weight staging vs 64-row blocks.
// ---------------------------------------------------------------------------
__global__ __launch_bounds__(512, 2) void k2a(
    const ushort_t* __restrict__ qs_bf,  // [20480][128]
    const ushort_t* __restrict__ wcomb,  // [256][128] (j-major)
    const float* __restrict__ b1,
    ushort_t* __restrict__ qw_bf,        // [20480][128]
    float* __restrict__ A)               // [20480][128]
{
    __shared__ __align__(16) ushort_t sh_w[256 * 136];
    const int tid = threadIdx.x;
    for (int i = tid * 4; i < 32768; i += 2048) {
        int j = i >> 7, k = i & 127;
        *(ushort4*)&sh_w[j * 136 + k] = *(const ushort4*)&wcomb[i];
    }
    __syncthreads();

    const int wave = tid >> 6, lane = tid & 63, m16 = lane & 15, q = lane >> 4;
    const size_t row = (size_t)blockIdx.x * 128 + wave * 16 + m16;

    floatx4 acc[16];
#pragma unroll
    for (int jt = 0; jt < 16; ++jt) acc[jt] = (floatx4){0.f, 0.f, 0.f, 0.f};

#pragma unroll
    for (int kt = 0; kt < 4; ++kt) {
        bf16x8 a = *(const bf16x8*)&qs_bf[row * 128 + kt * 32 + q * 8];
#pragma unroll
        for (int jt = 0; jt < 16; ++jt) {
            bf16x8 b = *(const bf16x8*)&sh_w[(jt * 16 + m16) * 136 + kt * 32 + q * 8];
            acc[jt] = __builtin_amdgcn_mfma_f32_16x16x32_bf16(a, b, acc[jt], 0, 0, 0);
        }
    }

    const size_t orow0 = (size_t)blockIdx.x * 128 + wave * 16 + q * 4;
#pragma unroll
    for (int jt = 0; jt < 16; ++jt) {
        int col = jt * 16 + m16;
        if (col < 128) {
#pragma unroll
            for (int reg = 0; reg < 4; ++reg)
                qw_bf[(orow0 + reg) * 128 + col] = f2bf(acc[jt][reg]);
        } else {
            float bv = b1[col - 128];
#pragma unroll
            for (int reg = 0; reg < 4; ++reg)
                A[(orow0 + reg) * 128 + (col - 128)] = acc[jt][reg] + bv;
        }
    }
}

// ---------------------------------------------------------------------------
// K2b (MFMA): QS1^T = (qstat_bf @ W1bot)^T, stored [b][u][xn] so k4 can read
// K(=xn)-contiguous b128 A-fragments.  128 blocks x 64 rows.
// ---------------------------------------------------------------------------
__global__ __launch_bounds__(256) void k2b(
    const ushort_t* __restrict__ qstat_bf,
    const ushort_t* __restrict__ w1botT,
    ushort_t* __restrict__ qs1T_bf)      // [B][128 u][128 xn]
{
    __shared__ __align__(16) ushort_t sh_w[128 * 136];
    const int tid = threadIdx.x;
    for (int i = tid * 4; i < 16384; i += 1024) {
        int j = i >> 7, k = i & 127;
        *(ushort4*)&sh_w[j * 136 + k] = *(const ushort4*)&w1botT[i];
    }
    __syncthreads();

    const int wave = tid >> 6, lane = tid & 63, m16 = lane & 15, q = lane >> 4;
    const size_t row = (size_t)blockIdx.x * 64 + wave * 16 + m16;

    floatx4 acc[8];
#pragma unroll
    for (int jt = 0; jt < 8; ++jt) acc[jt] = (floatx4){0.f, 0.f, 0.f, 0.f};
#pragma unroll
    for (int kt = 0; kt < 4; ++kt) {
        bf16x8 a = *(const bf16x8*)&qstat_bf[row * 128 + kt * 32 + q * 8];
#pragma unroll
        for (int jt = 0; jt < 8; ++jt) {
            bf16x8 b = *(const bf16x8*)&sh_w[(jt * 16 + m16) * 136 + kt * 32 + q * 8];
            acc[jt] = __builtin_amdgcn_mfma_f32_16x16x32_bf16(a, b, acc[jt], 0, 0, 0);
        }
    }
    const size_t orow0 = (size_t)blockIdx.x * 64 + wave * 16 + q * 4;
#pragma unroll
    for (int jt = 0; jt < 8; ++jt) {
        int col = jt * 16 + m16;                 // u
#pragma unroll
        for (int reg = 0; reg < 4; ++reg) {
            size_t grow = orow0 + reg;           // global xn-row = b*128 + xn
            qs1T_bf[(grow >> 7) * 16384 + (size_t)col * 128 + (grow & 127)]
                = f2bf(acc[jt][reg]);
        }
    }
}

// ---------------------------------------------------------------------------
// K3 (MFMA): co[b] = qw[b] @ qstat[b]^T (fp32 out).  grid (5, 64).
// ---------------------------------------------------------------------------
__global__ __launch_bounds__(256) void k3_co(
    const ushort_t* __restrict__ qw_bf,
    const ushort_t* __restrict__ qstat_bf,
    float* __restrict__ co)
{
    __shared__ __align__(16) ushort_t sh_y[128 * 136];
    const int tid = threadIdx.x, rt = blockIdx.x, b = blockIdx.y;
    for (int i = tid * 4; i < 16384; i += 1024) {
        int j = i >> 7, k = i & 127;
        *(ushort4*)&sh_y[j * 136 + k] = *(const ushort4*)&qstat_bf[(size_t)b * 16384 + i];
    }
    __syncthreads();

    const int wave = tid >> 6, lane = tid & 63, m16 = lane & 15, q = lane >> 4;
    const size_t rbase = (size_t)b * 320 + rt * 64 + wave * 16;

    floatx4 acc[8];
#pragma unroll
    for (int jt = 0; jt < 8; ++jt) acc[jt] = (floatx4){0.f, 0.f, 0.f, 0.f};
#pragma unroll
    for (int kt = 0; kt < 4; ++kt) {
        bf16x8 a = *(const bf16x8*)&qw_bf[(rbase + m16) * 128 + kt * 32 + q * 8];
#pragma unroll
        for (int jt = 0; jt < 8; ++jt) {
            bf16x8 b2_ = *(const bf16x8*)&sh_y[(jt * 16 + m16) * 136 + kt * 32 + q * 8];
            acc[jt] = __builtin_amdgcn_mfma_f32_16x16x32_bf16(a, b2_, acc[jt], 0, 0, 0);
        }
    }
#pragma unroll
    for (int jt = 0; jt < 8; ++jt)
#pragma unroll
        for (int reg = 0; reg < 4; ++reg)
            co[(rbase + q * 4 + reg) * 128 + jt * 16 + m16] = acc[jt][reg];
}

// ---------------------------------------------------------------------------
// K4 (fully-MFMA fused): per bw:
//  (1) softmax(x) -> p2 bf16 [s][xn] in LDS
//  (2) h1^T = QS1^T @ P2big^T via MFMA: A-frag b128 from qs1T (K=xn contig),
//      B-frag synthesized in registers (one nonzero/lane: pf[e]=(e==n)?p2:0).
//      Wave w owns sn-coltile w -> gacc[8] = 32 VGPRs, all bounds static.
//  (3) h1 = relu(gacc + A) -> packed b64 writes into LDS (reusing qs1T/p2
//      region after a barrier; 78 KB total -> 2 blocks/CU)
//  (4) h2 GEMM + epilogue as before.
// Replaces R6's VALU h1-loop (~1000 ops/thread) + conflicted gathers.
// ---------------------------------------------------------------------------
__global__ __launch_bounds__(640, 5) void k4_fused(
    const float* __restrict__ co,          // [B][320][128]
    const ushort_t* __restrict__ qs1T_bf,  // [B][128 u][128 xn]
    const float* __restrict__ A,           // [B*W*20][128]
    const ushort_t* __restrict__ w2T,      // [128][128] (j-major)
    const float* __restrict__ b2,
    const float* __restrict__ W3,
    const float* __restrict__ b3,
    float* __restrict__ lg)                // [B*W][160]
{
    __shared__ __align__(16) ushort_t sh_w2t[128 * 136];  // 34816 B
    __shared__ __align__(16) ushort_t sh_u[160 * 136];    // 43520 B union:
    // phase A: [0..17407] = qs1T [u][xn] (stride 136); [17408 + s*132 + xn] = p2
    // phase B: [row_sn*136 + u] = h1 (bf16)

    const int bw = blockIdx.x, b = bw >> 4, tid = threadIdx.x;

    for (int i = tid * 4; i < 16384; i += 2560) {
        int r = i >> 7, k = i & 127;
        *(ushort4*)&sh_w2t[r * 136 + k] = *(const ushort4*)&w2T[i];
        *(ushort4*)&sh_u[r * 136 + k] = *(const ushort4*)&qs1T_bf[(size_t)b * 16384 + i];
    }

    if (tid < 160) {
        int s = tid >> 3, n = tid & 7;
        const float* crow = co + ((size_t)bw * 20 + s) * 128;
        float v[16];
        float m = -INFINITY;
#pragma unroll
        for (int x = 0; x < 16; ++x) {
            float t = crow[x * 8 + n];
            if (t == 0.0f) t = -INF_;
            v[x] = t;
            m = fmaxf(m, t);
        }
        float sum = 0.f;
#pragma unroll
        for (int x = 0; x < 16; ++x) { v[x] = expf(v[x] - m); sum += v[x]; }
        float r = 1.0f / sum;
#pragma unroll
        for (int x = 0; x < 16; ++x)
            sh_u[17408 + s * 132 + x * 8 + n] = f2bf(v[x] * r);
    }
    __syncthreads();

    const int wave = tid >> 6, lane = tid & 63, m16 = lane & 15, q = lane >> 4;
    const int n = m16 & 7;
    const int sIdx = wave * 2 + (m16 >> 3);   // s of this lane's sn-column
    const int rowS = wave * 16 + m16;         // sn = sIdx*8 + n

    // ---- h1^T MFMA: gacc[mt] = D'[u-tile mt][sn-col rowS] ----
    floatx4 gacc[8];
#pragma unroll
    for (int mt = 0; mt < 8; ++mt) gacc[mt] = (floatx4){0.f, 0.f, 0.f, 0.f};

#pragma unroll
    for (int kt = 0; kt < 4; ++kt) {
        short pv = (short)sh_u[17408 + sIdx * 132 + kt * 32 + q * 8 + n];
        bf16x8 pf = {0, 0, 0, 0, 0, 0, 0, 0};
        pf[0] = (n == 0) ? pv : (short)0;
        pf[1] = (n == 1) ? pv : (short)0;
        pf[2] = (n == 2) ? pv : (short)0;
        pf[3] = (n == 3) ? pv : (short)0;
        pf[4] = (n == 4) ? pv : (short)0;
        pf[5] = (n == 5) ? pv : (short)0;
        pf[6] = (n == 6) ? pv : (short)0;
        pf[7] = (n == 7) ? pv : (short)0;
#pragma unroll
        for (int mt = 0; mt < 8; ++mt) {
            bf16x8 af = *(const bf16x8*)&sh_u[(mt * 16 + m16) * 136 + kt * 32 + q * 8];
            gacc[mt] = __builtin_amdgcn_mfma_f32_16x16x32_bf16(af, pf, gacc[mt], 0, 0, 0);
        }
    }
    __syncthreads();   // all qs1T/p2 reads done; union region may be rewritten

    // ---- h1 = relu(gacc + A[s][u]) -> bf16, packed b64 writes ----
    {
        const float* Ab = A + ((size_t)bw * 20 + sIdx) * 128;
#pragma unroll
        for (int mt = 0; mt < 8; ++mt) {
            int u0 = mt * 16 + q * 4;
            float4 av = *(const float4*)&Ab[u0];
            ushort4 o;
            o.x = f2bf(fmaxf(gacc[mt][0] + av.x, 0.f));
            o.y = f2bf(fmaxf(gacc[mt][1] + av.y, 0.f));
            o.z = f2bf(fmaxf(gacc[mt][2] + av.z, 0.f));
            o.w = f2bf(fmaxf(gacc[mt][3] + av.w, 0.f));
            *(ushort4*)&sh_u[rowS * 136 + u0] = o;
        }
    }
    __syncthreads();

    // ---- h2 GEMM: wave owns row-tile 'wave' ----
    floatx4 acc[8];
#pragma unroll
    for (int jt = 0; jt < 8; ++jt) acc[jt] = (floatx4){0.f, 0.f, 0.f, 0.f};

#pragma unroll
    for (int kt = 0; kt < 4; ++kt) {
        const int k0 = kt * 32 + q * 8;
        bf16x8 af = *(const bf16x8*)&sh_u[rowS * 136 + k0];
#pragma unroll
        for (int jt = 0; jt < 8; ++jt) {
            bf16x8 bfr = *(const bf16x8*)&sh_w2t[(jt * 16 + m16) * 136 + k0];
            acc[jt] = __builtin_amdgcn_mfma_f32_16x16x32_bf16(af, bfr, acc[jt], 0, 0, 0);
        }
    }

    float b2v[8], w3v[8];
#pragma unroll
    for (int jt = 0; jt < 8; ++jt) {
        b2v[jt] = b2[jt * 16 + m16];
        w3v[jt] = W3[jt * 16 + m16];
    }
    const float b3v = b3[0];

#pragma unroll
    for (int reg = 0; reg < 4; ++reg) {
        float p = 0.f;
#pragma unroll
        for (int jt = 0; jt < 8; ++jt)
            p += fmaxf(acc[jt][reg] + b2v[jt], 0.f) * w3v[jt];
        p += __shfl_xor(p, 1);
        p += __shfl_xor(p, 2);
        p += __shfl_xor(p, 4);
        p += __shfl_xor(p, 8);
        if (m16 == 0)
            lg[(size_t)bw * 160 + wave * 16 + q * 4 + reg] = p + b3v;
    }
}

// ---------------------------------------------------------------------------
// K5: masked max over W, labels, scalar.
// ---------------------------------------------------------------------------
__global__ __launch_bounds__(256) void k5_final(
    const float* __restrict__ lg,
    const float* __restrict__ mask,
    float* __restrict__ out)
{
    int idx = blockIdx.x * 256 + threadIdx.x;
    const int SN = S_ * N_;
    if (idx < B_ * SN) {
        int b = idx / SN, sn = idx % SN;
        float m = -INFINITY;
        for (int w = 0; w < W_; ++w) {
            float v = lg[((size_t)b * W_ + w) * SN + sn] + mask[((size_t)b * W_ + w) * SN + sn];
            m = fmaxf(m, v);
        }
        out[idx] = (m > 0.f) ? 1.f : 0.f;
        out[B_ * SN + 1 + idx] = m;
    }
    if (idx == 0) out[B_ * SN] = (float)SN;
}

// ---------------------------------------------------------------------------
extern "C" void kernel_launch(void* const* d_in, const int* in_sizes, int n_in,
                              void* d_out, int out_size, void* d_ws, size_t ws_size,
                              hipStream_t stream) {
    const float* slot_utt_h = (const float*)d_in[0];
    const float* slot_candidate_c = (const float*)d_in[1];
    const float* position_encoding = (const float*)d_in[3];
    const float* q_status = (const float*)d_in[4];
    const float* mask = (const float*)d_in[5];
    const float* weight = (const float*)d_in[6];
    const float* W1 = (const float*)d_in[7];
    const float* b1 = (const float*)d_in[8];
    const float* W2 = (const float*)d_in[9];
    const float* b2 = (const float*)d_in[10];
    const float* W3 = (const float*)d_in[11];
    const float* b3 = (const float*)d_in[12];
    float* out = (float*)d_out;

    float* f = (float*)d_ws;
    ushort_t* q_slot_bf = (ushort_t*)(f + 0);        // 2,621,440 sh
    ushort_t* qw_bf     = (ushort_t*)(f + 1310720);  // 2,621,440 sh
    float*    A         = f + 2621440;               // 2,621,440 f
    ushort_t* qs1T_bf   = (ushort_t*)(f + 5242880);  // 1,048,576 sh
    float*    co        = f + 5767168;               // 2,621,440 f
    float*    lg        = f + 8388608;               //   163,840 f
    ushort_t* qstat_bf  = (ushort_t*)(f + 8552448);  // 1,048,576 sh
    ushort_t* wcomb     = (ushort_t*)(f + 9076736);  //    32,768 sh
    ushort_t* w1botT    = (ushort_t*)(f + 9093120);  //    16,384 sh
    ushort_t* w2T       = (ushort_t*)(f + 9101312);  //    16,384 sh

    k0_cast<<<4352, 256, 0, stream>>>(q_status, weight, W1, W2,
                                      qstat_bf, wcomb, w1botT, w2T);
    k1_attn<<<1024, 256, 0, stream>>>(slot_utt_h, slot_candidate_c,
                                      position_encoding, q_slot_bf);
    k2b<<<128, 256, 0, stream>>>(qstat_bf, w1botT, qs1T_bf);
    k2a<<<160, 512, 0, stream>>>(q_slot_bf, wcomb, b1, qw_bf, A);
    k3_co<<<dim3(5, 64), 256, 0, stream>>>(qw_bf, qstat_bf, co);
    k4_fused<<<1024, 640, 0, stream>>>(co, qs1T_bf, A, w2T, b2, W3, b3, lg);
    k5_final<<<(B_ * S_ * N_ + 255) / 256, 256, 0, stream>>>(lg, mask, out);
}